// Round 9
// baseline (306.273 us; speedup 1.0000x reference)
//
#include <hip/hip_runtime.h>
#include <stdint.h>

#define N_NODES 4096
#define K_NN    40
#define B_CLOUDS 8
#define F_IN    8
#define H_DIM   64
#define O_DIM   128

#define OUT_FEAT_ELEMS (B_CLOUDS * N_NODES * O_DIM)   // 4194304
#define EDGES          (B_CLOUDS * N_NODES * K_NN)    // 1310720

typedef short bf16x8 __attribute__((ext_vector_type(8)));
typedef float f32x4  __attribute__((ext_vector_type(4)));

__device__ __forceinline__ unsigned short f2bf(float f) {
    unsigned u = __float_as_uint(f);
    unsigned r = (u + 0x7FFFu + ((u >> 16) & 1u)) >> 16;   // RNE
    return (unsigned short)r;
}

// wave_shr:1 — lane i receives lane i-1's value (COLD fallback path only).
__device__ __forceinline__ unsigned shr1_dpp(unsigned v) {
    return (unsigned)__builtin_amdgcn_update_dpp(0, (int)v, 0x138, 0xF, 0xF, true);
}

// One sorted-insert step (proven v3/v5 machinery) — COLD fallback only.
#define INS_STEP(mask_, dreg_, Rhi_, Rlo_)                                         \
    {                                                                              \
        const int src = (int)__builtin_ctzll(mask_);                               \
        mask_ &= mask_ - 1;                                                        \
        const unsigned long long kb =                                              \
            ((unsigned long long)(unsigned)__builtin_amdgcn_readlane((int)(dreg_), src) << 32) \
            | (unsigned)((c << 6) | src);                                          \
        const unsigned long long RP = ((unsigned long long)Rhi_ << 32) | Rlo_;     \
        const bool keep = (RP <= kb);                                              \
        const unsigned uplo = shr1_dpp(Rlo_);                                      \
        const unsigned uphi = shr1_dpp(Rhi_);                                      \
        const unsigned long long up = ((unsigned long long)uphi << 32) | uplo;     \
        const unsigned long long mx = (up > kb) ? up : kb;                         \
        const unsigned long long nw = keep ? RP : mx;                              \
        Rhi_ = (unsigned)(nw >> 32);                                               \
        Rlo_ = (unsigned)nw;                                                       \
    }

// Cheap wave-XOR shuffles for the bitonic stages (avoid ds_bpermute):
#define DPPX1(v)  ((unsigned)__builtin_amdgcn_update_dpp(0, (int)(v), 0xB1, 0xF, 0xF, true)) // quad_perm xor1
#define DPPX2(v)  ((unsigned)__builtin_amdgcn_update_dpp(0, (int)(v), 0x4E, 0xF, 0xF, true)) // quad_perm xor2
#define SWZ4(v)   ((unsigned)__builtin_amdgcn_ds_swizzle((int)(v), 0x101F))                  // xor4
#define SWZ8(v)   ((unsigned)__builtin_amdgcn_ds_swizzle((int)(v), 0x201F))                  // xor8
#define SWZ16(v)  ((unsigned)__builtin_amdgcn_ds_swizzle((int)(v), 0x401F))                  // xor16
#define SX32(v)   ((unsigned)__shfl_xor((int)(v), 32, 64))                                   // xor32

// One bitonic compare-exchange stage on 4 u64 keys (4-way ILP).
#define CE4(K, J, SH)                                                            \
    {                                                                            \
        const bool up = (lane & (K)) == 0;                                       \
        const bool tk = ((lane & (J)) == 0) == up;                               \
        _Pragma("unroll")                                                        \
        for (int t = 0; t < 4; ++t) {                                            \
            const unsigned pl = SH((unsigned)key[t]);                            \
            const unsigned ph = SH((unsigned)(key[t] >> 32));                    \
            const unsigned long long pk = ((unsigned long long)ph << 32) | pl;   \
            const bool ls = key[t] < pk;                                         \
            const unsigned long long mn = ls ? key[t] : pk;                      \
            const unsigned long long mx = ls ? pk : key[t];                      \
            key[t] = tk ? mn : mx;                                               \
        }                                                                        \
    }

// ---------------------------------------------------------------------------
// Kernel A: exact KNN v12 — v11 pipeline, FOUR targets per wave.
// R8 accounting: VALU (~44us) + DS (~38us) nearly ADD (lockstep, 4 waves/SIMD)
// -> removing cycles on either pipe pays ~1:1. 4 targets/wave shares each
// ppos read 4 ways (reads/target 56 -> 31); VALU/target ~flat; prune weakens
// to ~60/64 chunks (union of 4) — accepted. qual = 32 KB -> 96 KB LDS, still
// 1 block/CU. ~50 live VGPR, launch_bounds(1024,4): no clamp, no spill.
// ---------------------------------------------------------------------------
__global__ __launch_bounds__(1024, 4) void knn_kernel(const float* __restrict__ pos,
                                                      float* __restrict__ out)
{
    __shared__ float4 ppos[N_NODES];                 // 64 KB
    __shared__ unsigned long long qual[16][4][64];   // 32 KB -> 96 KB total

    const int b  = blockIdx.x >> 6;           // 64 blocks per cloud
    const int i0 = (blockIdx.x & 63) << 6;    // 64 targets per block
    const float* posb = pos + (size_t)b * N_NODES * 3;

    for (int n = threadIdx.x; n < N_NODES; n += 1024) {
        ppos[n] = make_float4(posb[3 * n], posb[3 * n + 1], posb[3 * n + 2], 0.f);
    }
    __syncthreads();

    const int wave = threadIdx.x >> 6;
    const int lane = threadIdx.x & 63;
    const int iT = i0 + (wave << 2);          // targets iT..iT+3 (same chunk)

    float px[4], py[4], pz[4];
#pragma unroll
    for (int t = 0; t < 4; ++t) {
        const float4 p = ppos[iT + t];
        px[t] = p.x; py[t] = p.y; pz[t] = p.z;
    }

    // ---- pass 1 (transposed): lane l scans block l; 4 class-mins/target ----
    unsigned mn[4][4];
#pragma unroll
    for (int t = 0; t < 4; ++t)
#pragma unroll
        for (int k = 0; k < 4; ++k) mn[t][k] = ~0u;

#pragma unroll 4
    for (int c = 0; c < 64; ++c) {
        const int jj = (lane << 6) | (c ^ lane);   // block l, XOR-staggered
        const float4 p = ppos[jj];
#pragma unroll
        for (int t = 0; t < 4; ++t) {
            // bitwise-exact fp32: ((dx*dx + dy*dy) + dz*dz), no FMA contraction
            const float dx = __fsub_rn(px[t], p.x);
            const float dy = __fsub_rn(py[t], p.y);
            const float dz = __fsub_rn(pz[t], p.z);
            const float d2 = __fadd_rn(__fadd_rn(__fmul_rn(dx, dx), __fmul_rn(dy, dy)),
                                       __fmul_rn(dz, dz));
            mn[t][c & 3] = min(mn[t][c & 3], __float_as_uint(d2));
        }
    }

    // ---- truncated radix-select (4-way): t >= 40th real dist per target ----
    // kept = 256 per-(lane,class) mins incl. one artificial 0 (self); rank-41
    // of kept >= rank-40 of real; 18 bits + round-up => superset threshold.
    unsigned acc[4] = {0, 0, 0, 0};
    for (int bit = 30; bit >= 13; --bit) {
#pragma unroll
        for (int t = 0; t < 4; ++t) {
            const unsigned test = acc[t] | (1u << bit);
            const int cnt = __popcll(__ballot(mn[t][0] < test))
                          + __popcll(__ballot(mn[t][1] < test))
                          + __popcll(__ballot(mn[t][2] < test))
                          + __popcll(__ballot(mn[t][3] < test));
            if (cnt <= K_NN) acc[t] = test;
        }
    }
    unsigned th[4];
#pragma unroll
    for (int t = 0; t < 4; ++t) th[t] = acc[t] | 0x1FFFu;

    // ---- prune mask: bit l set iff block l holds a qualifier for any tgt ----
    unsigned long long sm = 0;
#pragma unroll
    for (int t = 0; t < 4; ++t) {
        const unsigned bm = min(min(mn[t][0], mn[t][1]), min(mn[t][2], mn[t][3]));
        sm |= __ballot(bm <= th[t]);
    }
    // self blocks always set (d2=0 <= th), so emit logic below is safe.

    // ---- pass 2: visit qualifying chunks; branch-free 4-way compaction ----
    int base[4] = {0, 0, 0, 0};
    while (sm) {
        const int c = (int)__builtin_ctzll(sm);
        sm &= sm - 1;
        const float4 p = ppos[(c << 6) | lane];
        const unsigned jj = (unsigned)((c << 6) | lane);
#pragma unroll
        for (int t = 0; t < 4; ++t) {
            const float dx = __fsub_rn(px[t], p.x);
            const float dy = __fsub_rn(py[t], p.y);
            const float dz = __fsub_rn(pz[t], p.z);
            const float d2 = __fadd_rn(__fadd_rn(__fmul_rn(dx, dx), __fmul_rn(dy, dy)),
                                       __fmul_rn(dz, dz));
            const unsigned d2b = __float_as_uint(d2);
            const bool q = d2b <= th[t];
            const unsigned long long mk = __ballot(q);
            const unsigned mb = __builtin_amdgcn_mbcnt_hi(
                (unsigned)(mk >> 32), __builtin_amdgcn_mbcnt_lo((unsigned)mk, 0u));
            const int idx = base[t] + (int)mb;
            if (q && idx < 64)
                qual[wave][t][idx] = ((unsigned long long)d2b << 32) | jj;
            base[t] += (int)__popcll(mk);
        }
    }

    float* src_out = out + OUT_FEAT_ELEMS;
    float* tgt_out = src_out + EDGES;

    if (base[0] <= 64 && base[1] <= 64 && base[2] <= 64 && base[3] <= 64) {
        // ---- four interleaved bitonic sorts, DS-light shuffles ----
        unsigned long long key[4];
#pragma unroll
        for (int t = 0; t < 4; ++t)
            key[t] = (lane < base[t]) ? qual[wave][t][lane] : ~0ull;
        CE4(2, 1, DPPX1)
        CE4(4, 2, DPPX2)  CE4(4, 1, DPPX1)
        CE4(8, 4, SWZ4)   CE4(8, 2, DPPX2)  CE4(8, 1, DPPX1)
        CE4(16, 8, SWZ8)  CE4(16, 4, SWZ4)  CE4(16, 2, DPPX2) CE4(16, 1, DPPX1)
        CE4(32, 16, SWZ16) CE4(32, 8, SWZ8) CE4(32, 4, SWZ4)  CE4(32, 2, DPPX2) CE4(32, 1, DPPX1)
        CE4(64, 32, SX32) CE4(64, 16, SWZ16) CE4(64, 8, SWZ8) CE4(64, 4, SWZ4)  CE4(64, 2, DPPX2) CE4(64, 1, DPPX1)
        // locate selves (low word == target id; d2=0 always qualifies), emit
#pragma unroll
        for (int t = 0; t < 4; ++t) {
            const unsigned lo = (unsigned)key[t];
            const int gi = b * N_NODES + iT + t;
            const int ps = (int)__builtin_ctzll(__ballot(lo == (unsigned)(iT + t)));
            const int el = lane - (lane > ps ? 1 : 0);
            if (lane != ps && el < K_NN) {
                src_out[(size_t)gi * K_NN + el] = (float)(b * N_NODES + (int)lo);
                tgt_out[(size_t)gi * K_NN + el] = (float)gi;
            }
        }
    } else {
        // ---- COLD exact fallback (P~1e-5): full sweep, serial insert x4 ----
        const int ci = iT >> 6;
        unsigned RAhi = (lane == 0) ? 0u : 0xFFFFFFFFu;
        unsigned RAlo = RAhi, RBhi = RAhi, RBlo = RAhi;
        unsigned RChi = RAhi, RClo = RAhi, RDhi = RAhi, RDlo = RAhi;
        if (lane == 0) { RAlo = RBlo = RClo = RDlo = 0u; }
        for (int c = 0; c < 64; ++c) {
            const float4 p = ppos[(c << 6) | lane];
            unsigned d[4];
#pragma unroll
            for (int t = 0; t < 4; ++t) {
                const float dx = __fsub_rn(px[t], p.x);
                const float dy = __fsub_rn(py[t], p.y);
                const float dz = __fsub_rn(pz[t], p.z);
                const float d2 = __fadd_rn(__fadd_rn(__fmul_rn(dx, dx), __fmul_rn(dy, dy)),
                                           __fmul_rn(dz, dz));
                d[t] = __float_as_uint(d2);
            }
            unsigned long long mk[4];
#pragma unroll
            for (int t = 0; t < 4; ++t) {
                mk[t] = __ballot(d[t] <= th[t]);
                if (c == ci) mk[t] &= ~(1ull << ((iT + t) & 63));   // drop self
            }
            { unsigned long long mask = mk[0]; const unsigned dd = d[0];
              while (mask) INS_STEP(mask, dd, RAhi, RAlo); }
            { unsigned long long mask = mk[1]; const unsigned dd = d[1];
              while (mask) INS_STEP(mask, dd, RBhi, RBlo); }
            { unsigned long long mask = mk[2]; const unsigned dd = d[2];
              while (mask) INS_STEP(mask, dd, RChi, RClo); }
            { unsigned long long mask = mk[3]; const unsigned dd = d[3];
              while (mask) INS_STEP(mask, dd, RDhi, RDlo); }
        }
        const unsigned el = (unsigned)(lane - 1);
        if (el < K_NN) {
            const int g0 = b * N_NODES + iT;
            src_out[(size_t)(g0 + 0) * K_NN + el] = (float)(b * N_NODES + (int)RAlo);
            tgt_out[(size_t)(g0 + 0) * K_NN + el] = (float)(g0 + 0);
            src_out[(size_t)(g0 + 1) * K_NN + el] = (float)(b * N_NODES + (int)RBlo);
            tgt_out[(size_t)(g0 + 1) * K_NN + el] = (float)(g0 + 1);
            src_out[(size_t)(g0 + 2) * K_NN + el] = (float)(b * N_NODES + (int)RClo);
            tgt_out[(size_t)(g0 + 2) * K_NN + el] = (float)(g0 + 2);
            src_out[(size_t)(g0 + 3) * K_NN + el] = (float)(b * N_NODES + (int)RDlo);
            tgt_out[(size_t)(g0 + 3) * K_NN + el] = (float)(g0 + 3);
        }
    }
}

// ---------------------------------------------------------------------------
// Kernel P: precompute W2 and W1 bf16 B-fragments into d_ws — R14, proven.
// ---------------------------------------------------------------------------
__global__ __launch_bounds__(256) void prep_kernel(const float* __restrict__ W2,
                                                   const float* __restrict__ W1,
                                                   unsigned short* __restrict__ ws)
{
    const int idx = blockIdx.x * 256 + threadIdx.x;   // 0..10239
    if (idx < 8192) {
        const int j    = idx & 7;
        const int lane = (idx >> 3) & 63;
        const int kt   = (idx >> 9) & 1;
        const int nt   = idx >> 10;
        const int k = kt * 32 + (lane >> 4) * 8 + j;
        const int n = nt * 16 + (lane & 15);
        ws[idx] = f2bf(W2[k * O_DIM + n]);
    } else if (idx < 8192 + 2048) {
        const int t = idx - 8192;
        const int j    = t & 7;
        const int lane = (t >> 3) & 63;
        const int nt   = t >> 9;          // 0..3
        const int k = (lane >> 4) * 8 + j;          // 0..31
        const int n = nt * 16 + (lane & 15);        // hidden channel
        ws[idx] = (k < 11) ? f2bf(W1[k * H_DIM + n]) : (unsigned short)0;
    }
}

// ---------------------------------------------------------------------------
// Kernel B: per-edge MLP, both layers MFMA. R9 change: H-store packs pairs of
// bf16 via DPP lane-pairing -> 24 ds_write_b32 instead of 48 ds_write_b16.
// ---------------------------------------------------------------------------
#define HSTR 72   // Hh row stride (bf16): 144 B
#define KSTR 40   // msg row stride (bf16): 80 B, 16B-aligned rows

__global__ __launch_bounds__(256, 4) void conv_kernel(
    const float* __restrict__ x, const float* __restrict__ pos,
    const unsigned short* __restrict__ w2f,   // d_ws: w2 frags [0,8192)
    const unsigned short* __restrict__ w1f,   // d_ws: w1 frags [8192,10240)
    const float* __restrict__ b1, const float* __restrict__ b2,
    float* __restrict__ out)
{
    __shared__ __align__(16) unsigned short Hh[4][48 * HSTR];    // 27648 B

    const int b    = blockIdx.x >> 10;
    const int i0   = (blockIdx.x & 1023) << 2;
    const int wave = threadIdx.x >> 6;
    const int lane = threadIdx.x & 63;
    const int quad = lane >> 4;
    const int col  = lane & 15;
    const int i    = i0 + wave;
    const int gi   = b * N_NODES + i;

    unsigned short* Hw = Hh[wave];

    // ---- phase 1: lane n (<48) gathers message row n, stages bf16 to LDS ----
    const float* src_edges = out + OUT_FEAT_ELEMS;
    if (lane < 48) {
        int j;
        if (lane < K_NN) j = (int)src_edges[(size_t)gi * K_NN + lane] - b * N_NODES;
        else             j = i;   // rows 40..47: self row + pad dups (max-safe)
        const float* xr = x + ((size_t)b * N_NODES + j) * F_IN;
        float4 xa = *(const float4*)xr;
        float4 xb = *(const float4*)(xr + 4);
        const float* pj = pos + ((size_t)b * N_NODES + j) * 3;
        const float* pi = pos + ((size_t)b * N_NODES + i) * 3;
        unsigned w[16];
#pragma unroll
        for (int t = 0; t < 16; ++t) w[t] = 0;
        w[0] = (unsigned)f2bf(xa.x) | ((unsigned)f2bf(xa.y) << 16);
        w[1] = (unsigned)f2bf(xa.z) | ((unsigned)f2bf(xa.w) << 16);
        w[2] = (unsigned)f2bf(xb.x) | ((unsigned)f2bf(xb.y) << 16);
        w[3] = (unsigned)f2bf(xb.z) | ((unsigned)f2bf(xb.w) << 16);
        w[4] = (unsigned)f2bf(pj[0] - pi[0]) | ((unsigned)f2bf(pj[1] - pi[1]) << 16);
        w[5] = (unsigned)f2bf(pj[2] - pi[2]);
        unsigned* mrow = (unsigned*)(Hw + lane * KSTR);
        *(uint4*)(mrow)      = make_uint4(w[0], w[1], w[2], w[3]);
        *(uint4*)(mrow + 4)  = make_uint4(w[4], w[5], w[6], w[7]);
        *(uint4*)(mrow + 8)  = make_uint4(w[8], w[9], w[10], w[11]);
        *(uint4*)(mrow + 12) = make_uint4(w[12], w[13], w[14], w[15]);
    }
    // same-wave ds_write -> ds_read: ordered by lgkmcnt, no barrier needed

    // ---- layer 1 via MFMA: H[48x64] = msg[48x32] . W1[32x64] ----
    bf16x8 Am[3];
#pragma unroll
    for (int mt = 0; mt < 3; ++mt)
        Am[mt] = *(const bf16x8*)&Hw[(mt * 16 + col) * KSTR + quad * 8];

    const bf16x8* W1f = (const bf16x8*)w1f;
    float hreg[12][4];
#pragma unroll
    for (int nt = 0; nt < 4; ++nt) {
        bf16x8 Bn = W1f[nt * 64 + lane];
        const float bias = b1[nt * 16 + col];
        f32x4 d0 = {bias, bias, bias, bias};
        f32x4 d1 = d0, d2 = d0;
        d0 = __builtin_amdgcn_mfma_f32_16x16x32_bf16(Am[0], Bn, d0, 0, 0, 0);
        d1 = __builtin_amdgcn_mfma_f32_16x16x32_bf16(Am[1], Bn, d1, 0, 0, 0);
        d2 = __builtin_amdgcn_mfma_f32_16x16x32_bf16(Am[2], Bn, d2, 0, 0, 0);
#pragma unroll
        for (int r = 0; r < 4; ++r) {
            hreg[nt * 3 + 0][r] = fmaxf(d0[r], 0.0f);
            hreg[nt * 3 + 1][r] = fmaxf(d1[r], 0.0f);
            hreg[nt * 3 + 2][r] = fmaxf(d2[r], 0.0f);
        }
    }

    // msg fully consumed -> overwrite region as Hh[row][hidden].
    // Pack col pairs via DPP xor1 (pair (2k,2k+1) computes identical words);
    // even lanes write rows r=0,1; odd lanes write rows r=2,3. 24 b32 writes.
    {
        const int colp = col & ~1;
        const int r0 = (lane & 1) << 1;
#pragma unroll
        for (int nt = 0; nt < 4; ++nt)
#pragma unroll
            for (int mt = 0; mt < 3; ++mt) {
                unsigned pk0, pk1;
                {
                    const unsigned ov = (unsigned)f2bf(hreg[nt * 3 + mt][r0]);
                    const unsigned pv = DPPX1(ov);
                    pk0 = (lane & 1) ? (pv | (ov << 16)) : (ov | (pv << 16));
                }
                {
                    const unsigned ov = (unsigned)f2bf(hreg[nt * 3 + mt][r0 + 1]);
                    const unsigned pv = DPPX1(ov);
                    pk1 = (lane & 1) ? (pv | (ov << 16)) : (ov | (pv << 16));
                }
                *(unsigned*)&Hw[(mt * 16 + quad * 4 + r0) * HSTR + nt * 16 + colp] = pk0;
                *(unsigned*)&Hw[(mt * 16 + quad * 4 + r0 + 1) * HSTR + nt * 16 + colp] = pk1;
            }
    }

    // ---- layer 2 via MFMA ----
    bf16x8 Af[3][2];
#pragma unroll
    for (int mt = 0; mt < 3; ++mt)
#pragma unroll
        for (int kt = 0; kt < 2; ++kt)
            Af[mt][kt] = *(const bf16x8*)&Hw[(mt * 16 + col) * HSTR + kt * 32 + quad * 8];

    const bf16x8* Bws = (const bf16x8*)w2f;
#pragma unroll
    for (int nt = 0; nt < 8; ++nt) {
        bf16x8 B0 = Bws[nt * 128 + lane];
        bf16x8 B1 = Bws[nt * 128 + 64 + lane];

        f32x4 c0 = {0.f, 0.f, 0.f, 0.f};
        f32x4 c1 = {0.f, 0.f, 0.f, 0.f};
        f32x4 c2 = {0.f, 0.f, 0.f, 0.f};
        c0 = __builtin_amdgcn_mfma_f32_16x16x32_bf16(Af[0][0], B0, c0, 0, 0, 0);
        c1 = __builtin_amdgcn_mfma_f32_16x16x32_bf16(Af[1][0], B0, c1, 0, 0, 0);
        c2 = __builtin_amdgcn_mfma_f32_16x16x32_bf16(Af[2][0], B0, c2, 0, 0, 0);
        c0 = __builtin_amdgcn_mfma_f32_16x16x32_bf16(Af[0][1], B1, c0, 0, 0, 0);
        c1 = __builtin_amdgcn_mfma_f32_16x16x32_bf16(Af[1][1], B1, c1, 0, 0, 0);
        c2 = __builtin_amdgcn_mfma_f32_16x16x32_bf16(Af[2][1], B1, c2, 0, 0, 0);

        float vm = c0[0];
        vm = fmaxf(vm, c0[1]); vm = fmaxf(vm, c0[2]); vm = fmaxf(vm, c0[3]);
        vm = fmaxf(vm, c1[0]); vm = fmaxf(vm, c1[1]); vm = fmaxf(vm, c1[2]); vm = fmaxf(vm, c1[3]);
        vm = fmaxf(vm, c2[0]); vm = fmaxf(vm, c2[1]); vm = fmaxf(vm, c2[2]); vm = fmaxf(vm, c2[3]);
        vm = fmaxf(vm, __shfl_xor(vm, 16));
        vm = fmaxf(vm, __shfl_xor(vm, 32));
        vm += b2[nt * 16 + col];

        if (lane < 16) out[(size_t)gi * O_DIM + nt * 16 + lane] = vm;
    }
}

// ---------------------------------------------------------------------------
extern "C" void kernel_launch(void* const* d_in, const int* in_sizes, int n_in,
                              void* d_out, int out_size, void* d_ws, size_t ws_size,
                              hipStream_t stream) {
    const float* x   = (const float*)d_in[0];
    const float* pos = (const float*)d_in[1];
    const float* W1  = (const float*)d_in[2];
    const float* b1  = (const float*)d_in[3];
    const float* W2  = (const float*)d_in[4];
    const float* b2  = (const float*)d_in[5];
    float* out = (float*)d_out;
    unsigned short* ws = (unsigned short*)d_ws;   // 10240 bf16 = 20.5 KB

    prep_kernel<<<40, 256, 0, stream>>>(W2, W1, ws);
    knn_kernel<<<(B_CLOUDS * N_NODES) / 64, 1024, 0, stream>>>(pos, out);
    conv_kernel<<<(B_CLOUDS * N_NODES) / 4, 256, 0, stream>>>(
        x, pos, ws, ws + 8192, b1, b2, out);
}

// Round 10
// 193.016 us; speedup vs baseline: 1.5868x; 1.5868x over previous
//
#include <hip/hip_runtime.h>
#include <stdint.h>

#define N_NODES 4096
#define K_NN    40
#define B_CLOUDS 8
#define F_IN    8
#define H_DIM   64
#define O_DIM   128

#define OUT_FEAT_ELEMS (B_CLOUDS * N_NODES * O_DIM)   // 4194304
#define EDGES          (B_CLOUDS * N_NODES * K_NN)    // 1310720

typedef short bf16x8 __attribute__((ext_vector_type(8)));
typedef float f32x4  __attribute__((ext_vector_type(4)));

__device__ __forceinline__ unsigned short f2bf(float f) {
    unsigned u = __float_as_uint(f);
    unsigned r = (u + 0x7FFFu + ((u >> 16) & 1u)) >> 16;   // RNE
    return (unsigned short)r;
}

// wave_shr:1 — lane i receives lane i-1's value (COLD fallback path only).
__device__ __forceinline__ unsigned shr1_dpp(unsigned v) {
    return (unsigned)__builtin_amdgcn_update_dpp(0, (int)v, 0x138, 0xF, 0xF, true);
}

// One sorted-insert step (proven v3/v5 machinery) — COLD fallback only.
#define INS_STEP(mask_, dreg_, Rhi_, Rlo_)                                         \
    {                                                                              \
        const int src = (int)__builtin_ctzll(mask_);                               \
        mask_ &= mask_ - 1;                                                        \
        const unsigned long long kb =                                              \
            ((unsigned long long)(unsigned)__builtin_amdgcn_readlane((int)(dreg_), src) << 32) \
            | (unsigned)((c << 6) | src);                                          \
        const unsigned long long RP = ((unsigned long long)Rhi_ << 32) | Rlo_;     \
        const bool keep = (RP <= kb);                                              \
        const unsigned uplo = shr1_dpp(Rlo_);                                      \
        const unsigned uphi = shr1_dpp(Rhi_);                                      \
        const unsigned long long up = ((unsigned long long)uphi << 32) | uplo;     \
        const unsigned long long mx = (up > kb) ? up : kb;                         \
        const unsigned long long nw = keep ? RP : mx;                              \
        Rhi_ = (unsigned)(nw >> 32);                                               \
        Rlo_ = (unsigned)nw;                                                       \
    }

// Cheap wave-XOR shuffles for the bitonic stages (avoid ds_bpermute):
#define DPPX1(v)  ((unsigned)__builtin_amdgcn_update_dpp(0, (int)(v), 0xB1, 0xF, 0xF, true)) // quad_perm xor1
#define DPPX2(v)  ((unsigned)__builtin_amdgcn_update_dpp(0, (int)(v), 0x4E, 0xF, 0xF, true)) // quad_perm xor2
#define SWZ4(v)   ((unsigned)__builtin_amdgcn_ds_swizzle((int)(v), 0x101F))                  // xor4
#define SWZ8(v)   ((unsigned)__builtin_amdgcn_ds_swizzle((int)(v), 0x201F))                  // xor8
#define SWZ16(v)  ((unsigned)__builtin_amdgcn_ds_swizzle((int)(v), 0x401F))                  // xor16
#define SX32(v)   ((unsigned)__shfl_xor((int)(v), 32, 64))                                   // xor32

// One bitonic compare-exchange stage on 4 u64 keys (4-way ILP).
#define CE4(K, J, SH)                                                            \
    {                                                                            \
        const bool up = (lane & (K)) == 0;                                       \
        const bool tk = ((lane & (J)) == 0) == up;                               \
        _Pragma("unroll")                                                        \
        for (int t = 0; t < 4; ++t) {                                            \
            const unsigned pl = SH((unsigned)key[t]);                            \
            const unsigned ph = SH((unsigned)(key[t] >> 32));                    \
            const unsigned long long pk = ((unsigned long long)ph << 32) | pl;   \
            const bool ls = key[t] < pk;                                         \
            const unsigned long long mn = ls ? key[t] : pk;                      \
            const unsigned long long mx = ls ? pk : key[t];                      \
            key[t] = tk ? mn : mx;                                               \
        }                                                                        \
    }

// ---------------------------------------------------------------------------
// Kernel A: exact KNN v13 — 4 targets/wave INSIDE the 80 KB LDS budget.
// R9 lesson: qual at 32 KB pushed total LDS to 96 KB -> 1 block/CU, gain
// cancelled. v13 shrinks positions to split SoA: pxy (float2, 32 KB) +
// pz (float, 16 KB) + qual 32 KB = exactly 80 KB -> 2 blocks/CU preserved.
// Per-chunk read = ds_read_b64 + ds_read_b32 (~same pipe cycles as one b128)
// now shared by 4 targets: read cycles/target ~halved vs R8.
// Bank check: transposed addr (lane<<6)|(c^lane): b64 hits each bank-pair
// exactly 4x (wave minimum, no excess); b32 2 lanes/bank (free).
// Live regs ~40-48 < 64 cap of launch_bounds(1024,8) — lean branch-free body.
// ---------------------------------------------------------------------------
__global__ __launch_bounds__(1024, 8) void knn_kernel(const float* __restrict__ pos,
                                                      float* __restrict__ out)
{
    __shared__ float2 pxy[N_NODES];                  // 32 KB
    __shared__ float  pzs[N_NODES];                  // 16 KB
    __shared__ unsigned long long qual[16][4][64];   // 32 KB -> 80 KB total

    const int b  = blockIdx.x >> 6;           // 64 blocks per cloud
    const int i0 = (blockIdx.x & 63) << 6;    // 64 targets per block
    const float* posb = pos + (size_t)b * N_NODES * 3;

    for (int n = threadIdx.x; n < N_NODES; n += 1024) {
        pxy[n] = make_float2(posb[3 * n], posb[3 * n + 1]);
        pzs[n] = posb[3 * n + 2];
    }
    __syncthreads();

    const int wave = threadIdx.x >> 6;
    const int lane = threadIdx.x & 63;
    const int iT = i0 + (wave << 2);          // targets iT..iT+3 (same chunk)

    float px[4], py[4], pz[4];
#pragma unroll
    for (int t = 0; t < 4; ++t) {
        const float2 p = pxy[iT + t];
        px[t] = p.x; py[t] = p.y; pz[t] = pzs[iT + t];
    }

    // ---- pass 1 (transposed): lane l scans block l; 4 class-mins/target ----
    unsigned mn[4][4];
#pragma unroll
    for (int t = 0; t < 4; ++t)
#pragma unroll
        for (int k = 0; k < 4; ++k) mn[t][k] = ~0u;

#pragma unroll 4
    for (int c = 0; c < 64; ++c) {
        const int jj = (lane << 6) | (c ^ lane);   // block l, XOR-staggered
        const float2 p = pxy[jj];
        const float zz = pzs[jj];
#pragma unroll
        for (int t = 0; t < 4; ++t) {
            // bitwise-exact fp32: ((dx*dx + dy*dy) + dz*dz), no FMA contraction
            const float dx = __fsub_rn(px[t], p.x);
            const float dy = __fsub_rn(py[t], p.y);
            const float dz = __fsub_rn(pz[t], zz);
            const float d2 = __fadd_rn(__fadd_rn(__fmul_rn(dx, dx), __fmul_rn(dy, dy)),
                                       __fmul_rn(dz, dz));
            mn[t][c & 3] = min(mn[t][c & 3], __float_as_uint(d2));
        }
    }

    // ---- truncated radix-select (4-way): t >= 40th real dist per target ----
    // kept = 256 per-(block,class) mins incl. one artificial 0 (self); rank-41
    // of kept >= rank-40 of real; 18 bits + round-up => superset threshold.
    unsigned acc[4] = {0, 0, 0, 0};
    for (int bit = 30; bit >= 13; --bit) {
#pragma unroll
        for (int t = 0; t < 4; ++t) {
            const unsigned test = acc[t] | (1u << bit);
            const int cnt = __popcll(__ballot(mn[t][0] < test))
                          + __popcll(__ballot(mn[t][1] < test))
                          + __popcll(__ballot(mn[t][2] < test))
                          + __popcll(__ballot(mn[t][3] < test));
            if (cnt <= K_NN) acc[t] = test;
        }
    }
    unsigned th[4];
#pragma unroll
    for (int t = 0; t < 4; ++t) th[t] = acc[t] | 0x1FFFu;

    // ---- prune mask: bit l set iff block l holds a qualifier for any tgt ----
    unsigned long long sm = 0;
#pragma unroll
    for (int t = 0; t < 4; ++t) {
        const unsigned bm = min(min(mn[t][0], mn[t][1]), min(mn[t][2], mn[t][3]));
        sm |= __ballot(bm <= th[t]);
    }
    // self blocks always set (d2=0 <= th), so emit logic below is safe.

    // ---- pass 2: visit qualifying chunks; branch-free 4-way compaction ----
    int base[4] = {0, 0, 0, 0};
    while (sm) {
        const int c = (int)__builtin_ctzll(sm);
        sm &= sm - 1;
        const int jj = (c << 6) | lane;
        const float2 p = pxy[jj];
        const float zz = pzs[jj];
#pragma unroll
        for (int t = 0; t < 4; ++t) {
            const float dx = __fsub_rn(px[t], p.x);
            const float dy = __fsub_rn(py[t], p.y);
            const float dz = __fsub_rn(pz[t], zz);
            const float d2 = __fadd_rn(__fadd_rn(__fmul_rn(dx, dx), __fmul_rn(dy, dy)),
                                       __fmul_rn(dz, dz));
            const unsigned d2b = __float_as_uint(d2);
            const bool q = d2b <= th[t];
            const unsigned long long mk = __ballot(q);
            const unsigned mb = __builtin_amdgcn_mbcnt_hi(
                (unsigned)(mk >> 32), __builtin_amdgcn_mbcnt_lo((unsigned)mk, 0u));
            const int idx = base[t] + (int)mb;
            if (q && idx < 64)
                qual[wave][t][idx] = ((unsigned long long)d2b << 32) | (unsigned)jj;
            base[t] += (int)__popcll(mk);
        }
    }

    float* src_out = out + OUT_FEAT_ELEMS;
    float* tgt_out = src_out + EDGES;

    if (base[0] <= 64 && base[1] <= 64 && base[2] <= 64 && base[3] <= 64) {
        // ---- four interleaved bitonic sorts, DS-light shuffles ----
        unsigned long long key[4];
#pragma unroll
        for (int t = 0; t < 4; ++t)
            key[t] = (lane < base[t]) ? qual[wave][t][lane] : ~0ull;
        CE4(2, 1, DPPX1)
        CE4(4, 2, DPPX2)  CE4(4, 1, DPPX1)
        CE4(8, 4, SWZ4)   CE4(8, 2, DPPX2)  CE4(8, 1, DPPX1)
        CE4(16, 8, SWZ8)  CE4(16, 4, SWZ4)  CE4(16, 2, DPPX2) CE4(16, 1, DPPX1)
        CE4(32, 16, SWZ16) CE4(32, 8, SWZ8) CE4(32, 4, SWZ4)  CE4(32, 2, DPPX2) CE4(32, 1, DPPX1)
        CE4(64, 32, SX32) CE4(64, 16, SWZ16) CE4(64, 8, SWZ8) CE4(64, 4, SWZ4)  CE4(64, 2, DPPX2) CE4(64, 1, DPPX1)
        // locate selves (low word == target id; d2=0 always qualifies), emit
#pragma unroll
        for (int t = 0; t < 4; ++t) {
            const unsigned lo = (unsigned)key[t];
            const int gi = b * N_NODES + iT + t;
            const int ps = (int)__builtin_ctzll(__ballot(lo == (unsigned)(iT + t)));
            const int el = lane - (lane > ps ? 1 : 0);
            if (lane != ps && el < K_NN) {
                src_out[(size_t)gi * K_NN + el] = (float)(b * N_NODES + (int)lo);
                tgt_out[(size_t)gi * K_NN + el] = (float)gi;
            }
        }
    } else {
        // ---- COLD exact fallback (P~1e-5): full sweep, serial insert x4 ----
        const int ci = iT >> 6;
        unsigned RAhi = (lane == 0) ? 0u : 0xFFFFFFFFu;
        unsigned RAlo = RAhi, RBhi = RAhi, RBlo = RAhi;
        unsigned RChi = RAhi, RClo = RAhi, RDhi = RAhi, RDlo = RAhi;
        for (int c = 0; c < 64; ++c) {
            const int jj = (c << 6) | lane;
            const float2 p = pxy[jj];
            const float zz = pzs[jj];
            unsigned d[4];
#pragma unroll
            for (int t = 0; t < 4; ++t) {
                const float dx = __fsub_rn(px[t], p.x);
                const float dy = __fsub_rn(py[t], p.y);
                const float dz = __fsub_rn(pz[t], zz);
                const float d2 = __fadd_rn(__fadd_rn(__fmul_rn(dx, dx), __fmul_rn(dy, dy)),
                                           __fmul_rn(dz, dz));
                d[t] = __float_as_uint(d2);
            }
            unsigned long long mk[4];
#pragma unroll
            for (int t = 0; t < 4; ++t) {
                mk[t] = __ballot(d[t] <= th[t]);
                if (c == ci) mk[t] &= ~(1ull << ((iT + t) & 63));   // drop self
            }
            { unsigned long long mask = mk[0]; const unsigned dd = d[0];
              while (mask) INS_STEP(mask, dd, RAhi, RAlo); }
            { unsigned long long mask = mk[1]; const unsigned dd = d[1];
              while (mask) INS_STEP(mask, dd, RBhi, RBlo); }
            { unsigned long long mask = mk[2]; const unsigned dd = d[2];
              while (mask) INS_STEP(mask, dd, RChi, RClo); }
            { unsigned long long mask = mk[3]; const unsigned dd = d[3];
              while (mask) INS_STEP(mask, dd, RDhi, RDlo); }
        }
        const unsigned el = (unsigned)(lane - 1);
        if (el < K_NN) {
            const int g0 = b * N_NODES + iT;
            src_out[(size_t)(g0 + 0) * K_NN + el] = (float)(b * N_NODES + (int)RAlo);
            tgt_out[(size_t)(g0 + 0) * K_NN + el] = (float)(g0 + 0);
            src_out[(size_t)(g0 + 1) * K_NN + el] = (float)(b * N_NODES + (int)RBlo);
            tgt_out[(size_t)(g0 + 1) * K_NN + el] = (float)(g0 + 1);
            src_out[(size_t)(g0 + 2) * K_NN + el] = (float)(b * N_NODES + (int)RClo);
            tgt_out[(size_t)(g0 + 2) * K_NN + el] = (float)(g0 + 2);
            src_out[(size_t)(g0 + 3) * K_NN + el] = (float)(b * N_NODES + (int)RDlo);
            tgt_out[(size_t)(g0 + 3) * K_NN + el] = (float)(g0 + 3);
        }
    }
}

// ---------------------------------------------------------------------------
// Kernel P: precompute W2 and W1 bf16 B-fragments into d_ws — R14, proven.
// ---------------------------------------------------------------------------
__global__ __launch_bounds__(256) void prep_kernel(const float* __restrict__ W2,
                                                   const float* __restrict__ W1,
                                                   unsigned short* __restrict__ ws)
{
    const int idx = blockIdx.x * 256 + threadIdx.x;   // 0..10239
    if (idx < 8192) {
        const int j    = idx & 7;
        const int lane = (idx >> 3) & 63;
        const int kt   = (idx >> 9) & 1;
        const int nt   = idx >> 10;
        const int k = kt * 32 + (lane >> 4) * 8 + j;
        const int n = nt * 16 + (lane & 15);
        ws[idx] = f2bf(W2[k * O_DIM + n]);
    } else if (idx < 8192 + 2048) {
        const int t = idx - 8192;
        const int j    = t & 7;
        const int lane = (t >> 3) & 63;
        const int nt   = t >> 9;          // 0..3
        const int k = (lane >> 4) * 8 + j;          // 0..31
        const int n = nt * 16 + (lane & 15);        // hidden channel
        ws[idx] = (k < 11) ? f2bf(W1[k * H_DIM + n]) : (unsigned short)0;
    }
}

// ---------------------------------------------------------------------------
// Kernel B: per-edge MLP, both layers MFMA — REVERTED to proven R8 version
// (R9's DPP-packed H-store used a runtime register index -> scratch spill:
//  FETCH 63 MB / WRITE 409 MB. Static-index scalar b16 stores are proven).
// ---------------------------------------------------------------------------
#define HSTR 72   // Hh row stride (bf16): 144 B
#define KSTR 40   // msg row stride (bf16): 80 B, 16B-aligned rows

__global__ __launch_bounds__(256, 4) void conv_kernel(
    const float* __restrict__ x, const float* __restrict__ pos,
    const unsigned short* __restrict__ w2f,   // d_ws: w2 frags [0,8192)
    const unsigned short* __restrict__ w1f,   // d_ws: w1 frags [8192,10240)
    const float* __restrict__ b1, const float* __restrict__ b2,
    float* __restrict__ out)
{
    __shared__ __align__(16) unsigned short Hh[4][48 * HSTR];    // 27648 B

    const int b    = blockIdx.x >> 10;
    const int i0   = (blockIdx.x & 1023) << 2;
    const int wave = threadIdx.x >> 6;
    const int lane = threadIdx.x & 63;
    const int quad = lane >> 4;
    const int col  = lane & 15;
    const int i    = i0 + wave;
    const int gi   = b * N_NODES + i;

    unsigned short* Hw = Hh[wave];

    // ---- phase 1: lane n (<48) gathers message row n, stages bf16 to LDS ----
    const float* src_edges = out + OUT_FEAT_ELEMS;
    if (lane < 48) {
        int j;
        if (lane < K_NN) j = (int)src_edges[(size_t)gi * K_NN + lane] - b * N_NODES;
        else             j = i;   // rows 40..47: self row + pad dups (max-safe)
        const float* xr = x + ((size_t)b * N_NODES + j) * F_IN;
        float4 xa = *(const float4*)xr;
        float4 xb = *(const float4*)(xr + 4);
        const float* pj = pos + ((size_t)b * N_NODES + j) * 3;
        const float* pi = pos + ((size_t)b * N_NODES + i) * 3;
        unsigned w[16];
#pragma unroll
        for (int t = 0; t < 16; ++t) w[t] = 0;
        w[0] = (unsigned)f2bf(xa.x) | ((unsigned)f2bf(xa.y) << 16);
        w[1] = (unsigned)f2bf(xa.z) | ((unsigned)f2bf(xa.w) << 16);
        w[2] = (unsigned)f2bf(xb.x) | ((unsigned)f2bf(xb.y) << 16);
        w[3] = (unsigned)f2bf(xb.z) | ((unsigned)f2bf(xb.w) << 16);
        w[4] = (unsigned)f2bf(pj[0] - pi[0]) | ((unsigned)f2bf(pj[1] - pi[1]) << 16);
        w[5] = (unsigned)f2bf(pj[2] - pi[2]);
        unsigned* mrow = (unsigned*)(Hw + lane * KSTR);
        *(uint4*)(mrow)      = make_uint4(w[0], w[1], w[2], w[3]);
        *(uint4*)(mrow + 4)  = make_uint4(w[4], w[5], w[6], w[7]);
        *(uint4*)(mrow + 8)  = make_uint4(w[8], w[9], w[10], w[11]);
        *(uint4*)(mrow + 12) = make_uint4(w[12], w[13], w[14], w[15]);
    }
    // same-wave ds_write -> ds_read: ordered by lgkmcnt, no barrier needed

    // ---- layer 1 via MFMA: H[48x64] = msg[48x32] . W1[32x64] ----
    bf16x8 Am[3];
#pragma unroll
    for (int mt = 0; mt < 3; ++mt)
        Am[mt] = *(const bf16x8*)&Hw[(mt * 16 + col) * KSTR + quad * 8];

    const bf16x8* W1f = (const bf16x8*)w1f;
    float hreg[12][4];
#pragma unroll
    for (int nt = 0; nt < 4; ++nt) {
        bf16x8 Bn = W1f[nt * 64 + lane];
        const float bias = b1[nt * 16 + col];
        f32x4 d0 = {bias, bias, bias, bias};
        f32x4 d1 = d0, d2 = d0;
        d0 = __builtin_amdgcn_mfma_f32_16x16x32_bf16(Am[0], Bn, d0, 0, 0, 0);
        d1 = __builtin_amdgcn_mfma_f32_16x16x32_bf16(Am[1], Bn, d1, 0, 0, 0);
        d2 = __builtin_amdgcn_mfma_f32_16x16x32_bf16(Am[2], Bn, d2, 0, 0, 0);
#pragma unroll
        for (int r = 0; r < 4; ++r) {
            hreg[nt * 3 + 0][r] = fmaxf(d0[r], 0.0f);
            hreg[nt * 3 + 1][r] = fmaxf(d1[r], 0.0f);
            hreg[nt * 3 + 2][r] = fmaxf(d2[r], 0.0f);
        }
    }

    // msg fully consumed -> overwrite region as Hh[row][hidden]
#pragma unroll
    for (int nt = 0; nt < 4; ++nt)
#pragma unroll
        for (int mt = 0; mt < 3; ++mt)
#pragma unroll
            for (int r = 0; r < 4; ++r)
                Hw[(mt * 16 + quad * 4 + r) * HSTR + nt * 16 + col] =
                    f2bf(hreg[nt * 3 + mt][r]);

    // ---- layer 2 via MFMA ----
    bf16x8 Af[3][2];
#pragma unroll
    for (int mt = 0; mt < 3; ++mt)
#pragma unroll
        for (int kt = 0; kt < 2; ++kt)
            Af[mt][kt] = *(const bf16x8*)&Hw[(mt * 16 + col) * HSTR + kt * 32 + quad * 8];

    const bf16x8* Bws = (const bf16x8*)w2f;
#pragma unroll
    for (int nt = 0; nt < 8; ++nt) {
        bf16x8 B0 = Bws[nt * 128 + lane];
        bf16x8 B1 = Bws[nt * 128 + 64 + lane];

        f32x4 c0 = {0.f, 0.f, 0.f, 0.f};
        f32x4 c1 = {0.f, 0.f, 0.f, 0.f};
        f32x4 c2 = {0.f, 0.f, 0.f, 0.f};
        c0 = __builtin_amdgcn_mfma_f32_16x16x32_bf16(Af[0][0], B0, c0, 0, 0, 0);
        c1 = __builtin_amdgcn_mfma_f32_16x16x32_bf16(Af[1][0], B0, c1, 0, 0, 0);
        c2 = __builtin_amdgcn_mfma_f32_16x16x32_bf16(Af[2][0], B0, c2, 0, 0, 0);
        c0 = __builtin_amdgcn_mfma_f32_16x16x32_bf16(Af[0][1], B1, c0, 0, 0, 0);
        c1 = __builtin_amdgcn_mfma_f32_16x16x32_bf16(Af[1][1], B1, c1, 0, 0, 0);
        c2 = __builtin_amdgcn_mfma_f32_16x16x32_bf16(Af[2][1], B1, c2, 0, 0, 0);

        float vm = c0[0];
        vm = fmaxf(vm, c0[1]); vm = fmaxf(vm, c0[2]); vm = fmaxf(vm, c0[3]);
        vm = fmaxf(vm, c1[0]); vm = fmaxf(vm, c1[1]); vm = fmaxf(vm, c1[2]); vm = fmaxf(vm, c1[3]);
        vm = fmaxf(vm, c2[0]); vm = fmaxf(vm, c2[1]); vm = fmaxf(vm, c2[2]); vm = fmaxf(vm, c2[3]);
        vm = fmaxf(vm, __shfl_xor(vm, 16));
        vm = fmaxf(vm, __shfl_xor(vm, 32));
        vm += b2[nt * 16 + col];

        if (lane < 16) out[(size_t)gi * O_DIM + nt * 16 + lane] = vm;
    }
}

// ---------------------------------------------------------------------------
extern "C" void kernel_launch(void* const* d_in, const int* in_sizes, int n_in,
                              void* d_out, int out_size, void* d_ws, size_t ws_size,
                              hipStream_t stream) {
    const float* x   = (const float*)d_in[0];
    const float* pos = (const float*)d_in[1];
    const float* W1  = (const float*)d_in[2];
    const float* b1  = (const float*)d_in[3];
    const float* W2  = (const float*)d_in[4];
    const float* b2  = (const float*)d_in[5];
    float* out = (float*)d_out;
    unsigned short* ws = (unsigned short*)d_ws;   // 10240 bf16 = 20.5 KB

    prep_kernel<<<40, 256, 0, stream>>>(W2, W1, ws);
    knn_kernel<<<(B_CLOUDS * N_NODES) / 64, 1024, 0, stream>>>(pos, out);
    conv_kernel<<<(B_CLOUDS * N_NODES) / 4, 256, 0, stream>>>(
        x, pos, ws, ws + 8192, b1, b2, out);
}

// Round 11
// 187.352 us; speedup vs baseline: 1.6347x; 1.0302x over previous
//
#include <hip/hip_runtime.h>
#include <stdint.h>

#define N_NODES 4096
#define K_NN    40
#define B_CLOUDS 8
#define F_IN    8
#define H_DIM   64
#define O_DIM   128

#define OUT_FEAT_ELEMS (B_CLOUDS * N_NODES * O_DIM)   // 4194304
#define EDGES          (B_CLOUDS * N_NODES * K_NN)    // 1310720

typedef short bf16x8 __attribute__((ext_vector_type(8)));
typedef float f32x4  __attribute__((ext_vector_type(4)));

__device__ __forceinline__ unsigned short f2bf(float f) {
    unsigned u = __float_as_uint(f);
    unsigned r = (u + 0x7FFFu + ((u >> 16) & 1u)) >> 16;   // RNE
    return (unsigned short)r;
}

// wave_shr:1 — lane i receives lane i-1's value (COLD fallback path only).
__device__ __forceinline__ unsigned shr1_dpp(unsigned v) {
    return (unsigned)__builtin_amdgcn_update_dpp(0, (int)v, 0x138, 0xF, 0xF, true);
}

// One sorted-insert step (proven v3/v5 machinery) — COLD fallback only.
#define INS_STEP(mask_, dreg_, Rhi_, Rlo_)                                         \
    {                                                                              \
        const int src = (int)__builtin_ctzll(mask_);                               \
        mask_ &= mask_ - 1;                                                        \
        const unsigned long long kb =                                              \
            ((unsigned long long)(unsigned)__builtin_amdgcn_readlane((int)(dreg_), src) << 32) \
            | (unsigned)((c << 6) | src);                                          \
        const unsigned long long RP = ((unsigned long long)Rhi_ << 32) | Rlo_;     \
        const bool keep = (RP <= kb);                                              \
        const unsigned uplo = shr1_dpp(Rlo_);                                      \
        const unsigned uphi = shr1_dpp(Rhi_);                                      \
        const unsigned long long up = ((unsigned long long)uphi << 32) | uplo;     \
        const unsigned long long mx = (up > kb) ? up : kb;                         \
        const unsigned long long nw = keep ? RP : mx;                              \
        Rhi_ = (unsigned)(nw >> 32);                                               \
        Rlo_ = (unsigned)nw;                                                       \
    }

// Cheap wave-XOR shuffles for the bitonic stages (avoid ds_bpermute):
#define DPPX1(v)  ((unsigned)__builtin_amdgcn_update_dpp(0, (int)(v), 0xB1, 0xF, 0xF, true)) // quad_perm xor1
#define DPPX2(v)  ((unsigned)__builtin_amdgcn_update_dpp(0, (int)(v), 0x4E, 0xF, 0xF, true)) // quad_perm xor2
#define SWZ4(v)   ((unsigned)__builtin_amdgcn_ds_swizzle((int)(v), 0x101F))                  // xor4
#define SWZ8(v)   ((unsigned)__builtin_amdgcn_ds_swizzle((int)(v), 0x201F))                  // xor8
#define SWZ16(v)  ((unsigned)__builtin_amdgcn_ds_swizzle((int)(v), 0x401F))                  // xor16
#define SX32(v)   ((unsigned)__shfl_xor((int)(v), 32, 64))                                   // xor32

// One bitonic compare-exchange stage on u64 keyA/keyB (A/B interleaved, ILP).
#define CE(K, J, SH)                                                         \
    {                                                                        \
        const unsigned pAl = SH((unsigned)keyA);                             \
        const unsigned pAh = SH((unsigned)(keyA >> 32));                     \
        const unsigned pBl = SH((unsigned)keyB);                             \
        const unsigned pBh = SH((unsigned)(keyB >> 32));                     \
        const unsigned long long pA = ((unsigned long long)pAh << 32) | pAl; \
        const unsigned long long pB = ((unsigned long long)pBh << 32) | pBl; \
        const bool up = (lane & (K)) == 0;                                   \
        const bool tk = ((lane & (J)) == 0) == up;                           \
        const bool lA = keyA < pA;                                           \
        const unsigned long long mnA = lA ? keyA : pA;                       \
        const unsigned long long mxA = lA ? pA : keyA;                       \
        keyA = tk ? mnA : mxA;                                               \
        const bool lB = keyB < pB;                                           \
        const unsigned long long mnB = lB ? keyB : pB;                       \
        const unsigned long long mxB = lB ? pB : keyB;                       \
        keyB = tk ? mnB : mxB;                                               \
    }

// ---------------------------------------------------------------------------
// Kernel A: exact KNN — REVERTED to the proven R8 v11 (84.2 µs, conflicts 0).
// R10's 4-target variant traded DS for VALU at a net loss (weaker prune,
// 4-way compaction ballots). v11 = 2 targets/wave + block-prune + DS-light
// bitonic is the measured optimum of this family.
// ---------------------------------------------------------------------------
__global__ __launch_bounds__(1024, 8) void knn_kernel(const float* __restrict__ pos,
                                                      float* __restrict__ out)
{
    __shared__ float4 ppos[N_NODES];                 // 64 KB
    __shared__ unsigned long long qual[16][2][64];   // 16 KB -> 80 KB total

    const int b  = blockIdx.x >> 7;           // 128 blocks per cloud
    const int i0 = (blockIdx.x & 127) << 5;   // 32 targets per block
    const float* posb = pos + (size_t)b * N_NODES * 3;

    for (int n = threadIdx.x; n < N_NODES; n += 1024) {
        ppos[n] = make_float4(posb[3 * n], posb[3 * n + 1], posb[3 * n + 2], 0.f);
    }
    __syncthreads();

    const int wave = threadIdx.x >> 6;
    const int lane = threadIdx.x & 63;
    const int iA = i0 + (wave << 1);
    const int iB = iA + 1;

    const float4 pa4 = ppos[iA];
    const float4 pb4 = ppos[iB];
    const float pax = pa4.x, pay = pa4.y, paz = pa4.z;
    const float pbx = pb4.x, pby = pb4.y, pbz = pb4.z;

    // ---- pass 1 (transposed): lane l covers block l; 4 class-mins each ----
    unsigned mA0 = ~0u, mA1 = ~0u, mA2 = ~0u, mA3 = ~0u;
    unsigned mB0 = ~0u, mB1 = ~0u, mB2 = ~0u, mB3 = ~0u;
#pragma unroll 8
    for (int c = 0; c < 64; ++c) {
        const int jj = (lane << 6) | (c ^ lane);   // block l, XOR-staggered
        const float4 p = ppos[jj];
        // bitwise-exact fp32: ((dx*dx + dy*dy) + dz*dz), no FMA contraction
        const float dxA = __fsub_rn(pax, p.x);
        const float dyA = __fsub_rn(pay, p.y);
        const float dzA = __fsub_rn(paz, p.z);
        const float d2A = __fadd_rn(__fadd_rn(__fmul_rn(dxA, dxA), __fmul_rn(dyA, dyA)),
                                    __fmul_rn(dzA, dzA));
        const float dxB = __fsub_rn(pbx, p.x);
        const float dyB = __fsub_rn(pby, p.y);
        const float dzB = __fsub_rn(pbz, p.z);
        const float d2B = __fadd_rn(__fadd_rn(__fmul_rn(dxB, dxB), __fmul_rn(dyB, dyB)),
                                    __fmul_rn(dzB, dzB));
        const unsigned dA = __float_as_uint(d2A);
        const unsigned dB = __float_as_uint(d2B);
        if ((c & 3) == 0)      { mA0 = min(mA0, dA); mB0 = min(mB0, dB); }
        else if ((c & 3) == 1) { mA1 = min(mA1, dA); mB1 = min(mB1, dB); }
        else if ((c & 3) == 2) { mA2 = min(mA2, dA); mB2 = min(mB2, dB); }
        else                   { mA3 = min(mA3, dA); mB3 = min(mB3, dB); }
    }

    // ---- truncated radix-select (A/B interleaved): t >= 40th real dist ----
    unsigned accA = 0, accB = 0;
    for (int bit = 30; bit >= 13; --bit) {
        const unsigned tA = accA | (1u << bit);
        const unsigned tB = accB | (1u << bit);
        const int cA = __popcll(__ballot(mA0 < tA)) + __popcll(__ballot(mA1 < tA))
                     + __popcll(__ballot(mA2 < tA)) + __popcll(__ballot(mA3 < tA));
        const int cB = __popcll(__ballot(mB0 < tB)) + __popcll(__ballot(mB1 < tB))
                     + __popcll(__ballot(mB2 < tB)) + __popcll(__ballot(mB3 < tB));
        if (cA <= K_NN) accA = tA;
        if (cB <= K_NN) accB = tB;
    }
    const unsigned thA = accA | 0x1FFFu;
    const unsigned thB = accB | 0x1FFFu;

    // ---- prune mask: bit l set iff block l holds a qualifier for A or B ----
    const unsigned bmA = min(min(mA0, mA1), min(mA2, mA3));
    const unsigned bmB = min(min(mB0, mB1), min(mB2, mB3));
    unsigned long long sm = __ballot(bmA <= thA) | __ballot(bmB <= thB);
    // self blocks always set (d2=0 <= th), so emit logic below is safe.

    // ---- pass 2: visit only qualifying chunks; branch-free compaction ----
    unsigned long long* qA = qual[wave][0];
    unsigned long long* qB = qual[wave][1];
    int baseA = 0, baseB = 0;
    while (sm) {
        const int c = (int)__builtin_ctzll(sm);
        sm &= sm - 1;
        const float4 p = ppos[(c << 6) | lane];
        const float dxA = __fsub_rn(pax, p.x);
        const float dyA = __fsub_rn(pay, p.y);
        const float dzA = __fsub_rn(paz, p.z);
        const float d2A = __fadd_rn(__fadd_rn(__fmul_rn(dxA, dxA), __fmul_rn(dyA, dyA)),
                                    __fmul_rn(dzA, dzA));
        const float dxB = __fsub_rn(pbx, p.x);
        const float dyB = __fsub_rn(pby, p.y);
        const float dzB = __fsub_rn(pbz, p.z);
        const float d2B = __fadd_rn(__fadd_rn(__fmul_rn(dxB, dxB), __fmul_rn(dyB, dyB)),
                                    __fmul_rn(dzB, dzB));
        const unsigned dA = __float_as_uint(d2A);
        const unsigned dB = __float_as_uint(d2B);
        const unsigned jj = (unsigned)((c << 6) | lane);

        const bool sA = dA <= thA;
        const unsigned long long mkA = __ballot(sA);
        const unsigned mbA = __builtin_amdgcn_mbcnt_hi(
            (unsigned)(mkA >> 32), __builtin_amdgcn_mbcnt_lo((unsigned)mkA, 0u));
        const int idxA = baseA + (int)mbA;
        if (sA && idxA < 64)
            qA[idxA] = ((unsigned long long)dA << 32) | jj;
        baseA += (int)__popcll(mkA);

        const bool sB = dB <= thB;
        const unsigned long long mkB = __ballot(sB);
        const unsigned mbB = __builtin_amdgcn_mbcnt_hi(
            (unsigned)(mkB >> 32), __builtin_amdgcn_mbcnt_lo((unsigned)mkB, 0u));
        const int idxB = baseB + (int)mbB;
        if (sB && idxB < 64)
            qB[idxB] = ((unsigned long long)dB << 32) | jj;
        baseB += (int)__popcll(mkB);
    }

    float* src_out = out + OUT_FEAT_ELEMS;
    float* tgt_out = src_out + EDGES;
    const int giA = b * N_NODES + iA;
    const int giB = giA + 1;

    if (baseA <= 64 && baseB <= 64) {
        // ---- interleaved bitonic, DS-light shuffles (21 stages) ----
        unsigned long long keyA = (lane < baseA) ? qA[lane] : ~0ull;
        unsigned long long keyB = (lane < baseB) ? qB[lane] : ~0ull;
        CE(2, 1, DPPX1)
        CE(4, 2, DPPX2)  CE(4, 1, DPPX1)
        CE(8, 4, SWZ4)   CE(8, 2, DPPX2)  CE(8, 1, DPPX1)
        CE(16, 8, SWZ8)  CE(16, 4, SWZ4)  CE(16, 2, DPPX2) CE(16, 1, DPPX1)
        CE(32, 16, SWZ16) CE(32, 8, SWZ8) CE(32, 4, SWZ4)  CE(32, 2, DPPX2) CE(32, 1, DPPX1)
        CE(64, 32, SX32) CE(64, 16, SWZ16) CE(64, 8, SWZ8) CE(64, 4, SWZ4)  CE(64, 2, DPPX2) CE(64, 1, DPPX1)
        // locate selves (low word == target id; d2=0 always qualifies), emit
        const unsigned loA = (unsigned)keyA;
        const unsigned loB = (unsigned)keyB;
        const int psA = (int)__builtin_ctzll(__ballot(loA == (unsigned)iA));
        const int psB = (int)__builtin_ctzll(__ballot(loB == (unsigned)iB));
        const int elA = lane - (lane > psA ? 1 : 0);
        const int elB = lane - (lane > psB ? 1 : 0);
        if (lane != psA && elA < K_NN) {
            src_out[(size_t)giA * K_NN + elA] = (float)(b * N_NODES + (int)loA);
            tgt_out[(size_t)giA * K_NN + elA] = (float)giA;
        }
        if (lane != psB && elB < K_NN) {
            src_out[(size_t)giB * K_NN + elB] = (float)(b * N_NODES + (int)loB);
            tgt_out[(size_t)giB * K_NN + elB] = (float)giB;
        }
    } else {
        // ---- COLD exact fallback (P~3e-6): full sweep, serial insert ----
        const int ci = iA >> 6;
        const int liA = iA & 63;
        const int liB = iB & 63;
        unsigned RAhi = (lane == 0) ? 0u : 0xFFFFFFFFu;
        unsigned RAlo = (lane == 0) ? 0u : 0xFFFFFFFFu;
        unsigned RBhi = RAhi, RBlo = RAlo;
        for (int c = 0; c < 64; ++c) {
            const float4 p = ppos[(c << 6) | lane];
            const float dxA = __fsub_rn(pax, p.x);
            const float dyA = __fsub_rn(pay, p.y);
            const float dzA = __fsub_rn(paz, p.z);
            const float d2A = __fadd_rn(__fadd_rn(__fmul_rn(dxA, dxA), __fmul_rn(dyA, dyA)),
                                        __fmul_rn(dzA, dzA));
            const float dxB = __fsub_rn(pbx, p.x);
            const float dyB = __fsub_rn(pby, p.y);
            const float dzB = __fsub_rn(pbz, p.z);
            const float d2B = __fadd_rn(__fadd_rn(__fmul_rn(dxB, dxB), __fmul_rn(dyB, dyB)),
                                        __fmul_rn(dzB, dzB));
            const unsigned dA = __float_as_uint(d2A);
            const unsigned dB = __float_as_uint(d2B);
            unsigned long long maskA = __ballot(dA <= thA);
            unsigned long long maskB = __ballot(dB <= thB);
            if (c == ci) {
                maskA &= ~(1ull << liA);
                maskB &= ~(1ull << liB);
            }
            while (maskA) INS_STEP(maskA, dA, RAhi, RAlo);
            while (maskB) INS_STEP(maskB, dB, RBhi, RBlo);
        }
        const unsigned el = (unsigned)(lane - 1);
        if (el < K_NN) {
            src_out[(size_t)giA * K_NN + el] = (float)(b * N_NODES + (int)RAlo);
            tgt_out[(size_t)giA * K_NN + el] = (float)giA;
            src_out[(size_t)giB * K_NN + el] = (float)(b * N_NODES + (int)RBlo);
            tgt_out[(size_t)giB * K_NN + el] = (float)giB;
        }
    }
}

// ---------------------------------------------------------------------------
// Kernel P: precompute W2 and W1 bf16 B-fragments into d_ws — R14, proven.
// ---------------------------------------------------------------------------
__global__ __launch_bounds__(256) void prep_kernel(const float* __restrict__ W2,
                                                   const float* __restrict__ W1,
                                                   unsigned short* __restrict__ ws)
{
    const int idx = blockIdx.x * 256 + threadIdx.x;   // 0..10239
    if (idx < 8192) {
        const int j    = idx & 7;
        const int lane = (idx >> 3) & 63;
        const int kt   = (idx >> 9) & 1;
        const int nt   = idx >> 10;
        const int k = kt * 32 + (lane >> 4) * 8 + j;
        const int n = nt * 16 + (lane & 15);
        ws[idx] = f2bf(W2[k * O_DIM + n]);
    } else if (idx < 8192 + 2048) {
        const int t = idx - 8192;
        const int j    = t & 7;
        const int lane = (t >> 3) & 63;
        const int nt   = t >> 9;          // 0..3
        const int k = (lane >> 4) * 8 + j;          // 0..31
        const int n = nt * 16 + (lane & 15);        // hidden channel
        ws[idx] = (k < 11) ? f2bf(W1[k * H_DIM + n]) : (unsigned short)0;
    }
}

// ---------------------------------------------------------------------------
// Kernel B: per-edge MLP, both layers MFMA — proven R8 body; occupancy bump
// 4 -> 5 blocks/CU (20 waves/CU). R9's polluted counters still showed
// latency-bound signature (MfmaUtil ~10%, VALUBusy ~24%, occ ~50%): +25% TLP
// should pay ~proportionally. VGPR cap at 5 waves/EU ~= 102 >= ~90 peak live.
// Spill gate: conv FETCH/WRITE ballooning (as in R9) -> revert to (256,4).
// ---------------------------------------------------------------------------
#define HSTR 72   // Hh row stride (bf16): 144 B
#define KSTR 40   // msg row stride (bf16): 80 B, 16B-aligned rows

__global__ __launch_bounds__(256, 5) void conv_kernel(
    const float* __restrict__ x, const float* __restrict__ pos,
    const unsigned short* __restrict__ w2f,   // d_ws: w2 frags [0,8192)
    const unsigned short* __restrict__ w1f,   // d_ws: w1 frags [8192,10240)
    const float* __restrict__ b1, const float* __restrict__ b2,
    float* __restrict__ out)
{
    __shared__ __align__(16) unsigned short Hh[4][48 * HSTR];    // 27648 B

    const int b    = blockIdx.x >> 10;
    const int i0   = (blockIdx.x & 1023) << 2;
    const int wave = threadIdx.x >> 6;
    const int lane = threadIdx.x & 63;
    const int quad = lane >> 4;
    const int col  = lane & 15;
    const int i    = i0 + wave;
    const int gi   = b * N_NODES + i;

    unsigned short* Hw = Hh[wave];

    // ---- phase 1: lane n (<48) gathers message row n, stages bf16 to LDS ----
    const float* src_edges = out + OUT_FEAT_ELEMS;
    if (lane < 48) {
        int j;
        if (lane < K_NN) j = (int)src_edges[(size_t)gi * K_NN + lane] - b * N_NODES;
        else             j = i;   // rows 40..47: self row + pad dups (max-safe)
        const float* xr = x + ((size_t)b * N_NODES + j) * F_IN;
        float4 xa = *(const float4*)xr;
        float4 xb = *(const float4*)(xr + 4);
        const float* pj = pos + ((size_t)b * N_NODES + j) * 3;
        const float* pi = pos + ((size_t)b * N_NODES + i) * 3;
        unsigned w[16];
#pragma unroll
        for (int t = 0; t < 16; ++t) w[t] = 0;
        w[0] = (unsigned)f2bf(xa.x) | ((unsigned)f2bf(xa.y) << 16);
        w[1] = (unsigned)f2bf(xa.z) | ((unsigned)f2bf(xa.w) << 16);
        w[2] = (unsigned)f2bf(xb.x) | ((unsigned)f2bf(xb.y) << 16);
        w[3] = (unsigned)f2bf(xb.z) | ((unsigned)f2bf(xb.w) << 16);
        w[4] = (unsigned)f2bf(pj[0] - pi[0]) | ((unsigned)f2bf(pj[1] - pi[1]) << 16);
        w[5] = (unsigned)f2bf(pj[2] - pi[2]);
        unsigned* mrow = (unsigned*)(Hw + lane * KSTR);
        *(uint4*)(mrow)      = make_uint4(w[0], w[1], w[2], w[3]);
        *(uint4*)(mrow + 4)  = make_uint4(w[4], w[5], w[6], w[7]);
        *(uint4*)(mrow + 8)  = make_uint4(w[8], w[9], w[10], w[11]);
        *(uint4*)(mrow + 12) = make_uint4(w[12], w[13], w[14], w[15]);
    }
    // same-wave ds_write -> ds_read: ordered by lgkmcnt, no barrier needed

    // ---- layer 1 via MFMA: H[48x64] = msg[48x32] . W1[32x64] ----
    bf16x8 Am[3];
#pragma unroll
    for (int mt = 0; mt < 3; ++mt)
        Am[mt] = *(const bf16x8*)&Hw[(mt * 16 + col) * KSTR + quad * 8];

    const bf16x8* W1f = (const bf16x8*)w1f;
    float hreg[12][4];
#pragma unroll
    for (int nt = 0; nt < 4; ++nt) {
        bf16x8 Bn = W1f[nt * 64 + lane];
        const float bias = b1[nt * 16 + col];
        f32x4 d0 = {bias, bias, bias, bias};
        f32x4 d1 = d0, d2 = d0;
        d0 = __builtin_amdgcn_mfma_f32_16x16x32_bf16(Am[0], Bn, d0, 0, 0, 0);
        d1 = __builtin_amdgcn_mfma_f32_16x16x32_bf16(Am[1], Bn, d1, 0, 0, 0);
        d2 = __builtin_amdgcn_mfma_f32_16x16x32_bf16(Am[2], Bn, d2, 0, 0, 0);
#pragma unroll
        for (int r = 0; r < 4; ++r) {
            hreg[nt * 3 + 0][r] = fmaxf(d0[r], 0.0f);
            hreg[nt * 3 + 1][r] = fmaxf(d1[r], 0.0f);
            hreg[nt * 3 + 2][r] = fmaxf(d2[r], 0.0f);
        }
    }

    // msg fully consumed -> overwrite region as Hh[row][hidden]
#pragma unroll
    for (int nt = 0; nt < 4; ++nt)
#pragma unroll
        for (int mt = 0; mt < 3; ++mt)
#pragma unroll
            for (int r = 0; r < 4; ++r)
                Hw[(mt * 16 + quad * 4 + r) * HSTR + nt * 16 + col] =
                    f2bf(hreg[nt * 3 + mt][r]);

    // ---- layer 2 via MFMA ----
    bf16x8 Af[3][2];
#pragma unroll
    for (int mt = 0; mt < 3; ++mt)
#pragma unroll
        for (int kt = 0; kt < 2; ++kt)
            Af[mt][kt] = *(const bf16x8*)&Hw[(mt * 16 + col) * HSTR + kt * 32 + quad * 8];

    const bf16x8* Bws = (const bf16x8*)w2f;
#pragma unroll
    for (int nt = 0; nt < 8; ++nt) {
        bf16x8 B0 = Bws[nt * 128 + lane];
        bf16x8 B1 = Bws[nt * 128 + 64 + lane];

        f32x4 c0 = {0.f, 0.f, 0.f, 0.f};
        f32x4 c1 = {0.f, 0.f, 0.f, 0.f};
        f32x4 c2 = {0.f, 0.f, 0.f, 0.f};
        c0 = __builtin_amdgcn_mfma_f32_16x16x32_bf16(Af[0][0], B0, c0, 0, 0, 0);
        c1 = __builtin_amdgcn_mfma_f32_16x16x32_bf16(Af[1][0], B0, c1, 0, 0, 0);
        c2 = __builtin_amdgcn_mfma_f32_16x16x32_bf16(Af[2][0], B0, c2, 0, 0, 0);
        c0 = __builtin_amdgcn_mfma_f32_16x16x32_bf16(Af[0][1], B1, c0, 0, 0, 0);
        c1 = __builtin_amdgcn_mfma_f32_16x16x32_bf16(Af[1][1], B1, c1, 0, 0, 0);
        c2 = __builtin_amdgcn_mfma_f32_16x16x32_bf16(Af[2][1], B1, c2, 0, 0, 0);

        float vm = c0[0];
        vm = fmaxf(vm, c0[1]); vm = fmaxf(vm, c0[2]); vm = fmaxf(vm, c0[3]);
        vm = fmaxf(vm, c1[0]); vm = fmaxf(vm, c1[1]); vm = fmaxf(vm, c1[2]); vm = fmaxf(vm, c1[3]);
        vm = fmaxf(vm, c2[0]); vm = fmaxf(vm, c2[1]); vm = fmaxf(vm, c2[2]); vm = fmaxf(vm, c2[3]);
        vm = fmaxf(vm, __shfl_xor(vm, 16));
        vm = fmaxf(vm, __shfl_xor(vm, 32));
        vm += b2[nt * 16 + col];

        if (lane < 16) out[(size_t)gi * O_DIM + nt * 16 + lane] = vm;
    }
}

// ---------------------------------------------------------------------------
extern "C" void kernel_launch(void* const* d_in, const int* in_sizes, int n_in,
                              void* d_out, int out_size, void* d_ws, size_t ws_size,
                              hipStream_t stream) {
    const float* x   = (const float*)d_in[0];
    const float* pos = (const float*)d_in[1];
    const float* W1  = (const float*)d_in[2];
    const float* b1  = (const float*)d_in[3];
    const float* W2  = (const float*)d_in[4];
    const float* b2  = (const float*)d_in[5];
    float* out = (float*)d_out;
    unsigned short* ws = (unsigned short*)d_ws;   // 10240 bf16 = 20.5 KB

    prep_kernel<<<40, 256, 0, stream>>>(W2, W1, ws);
    knn_kernel<<<(B_CLOUDS * N_NODES) / 32, 1024, 0, stream>>>(pos, out);
    conv_kernel<<<(B_CLOUDS * N_NODES) / 4, 256, 0, stream>>>(
        x, pos, ws, ws + 8192, b1, b2, out);
}

// Round 12
// 183.910 us; speedup vs baseline: 1.6653x; 1.0187x over previous
//
#include <hip/hip_runtime.h>
#include <stdint.h>

#define N_NODES 4096
#define K_NN    40
#define B_CLOUDS 8
#define F_IN    8
#define H_DIM   64
#define O_DIM   128

#define OUT_FEAT_ELEMS (B_CLOUDS * N_NODES * O_DIM)   // 4194304
#define EDGES          (B_CLOUDS * N_NODES * K_NN)    // 1310720

#define KNN_BLOCKS 1024
#define PREP_BLOCKS 10   // 10 x 1024 threads covers 10240 prep elements

typedef short bf16x8 __attribute__((ext_vector_type(8)));
typedef float f32x4  __attribute__((ext_vector_type(4)));

__device__ __forceinline__ unsigned short f2bf(float f) {
    unsigned u = __float_as_uint(f);
    unsigned r = (u + 0x7FFFu + ((u >> 16) & 1u)) >> 16;   // RNE
    return (unsigned short)r;
}

// wave_shr:1 — lane i receives lane i-1's value (COLD fallback path only).
__device__ __forceinline__ unsigned shr1_dpp(unsigned v) {
    return (unsigned)__builtin_amdgcn_update_dpp(0, (int)v, 0x138, 0xF, 0xF, true);
}

// One sorted-insert step (proven v3/v5 machinery) — COLD fallback only.
#define INS_STEP(mask_, dreg_, Rhi_, Rlo_)                                         \
    {                                                                              \
        const int src = (int)__builtin_ctzll(mask_);                               \
        mask_ &= mask_ - 1;                                                        \
        const unsigned long long kb =                                              \
            ((unsigned long long)(unsigned)__builtin_amdgcn_readlane((int)(dreg_), src) << 32) \
            | (unsigned)((c << 6) | src);                                          \
        const unsigned long long RP = ((unsigned long long)Rhi_ << 32) | Rlo_;     \
        const bool keep = (RP <= kb);                                              \
        const unsigned uplo = shr1_dpp(Rlo_);                                      \
        const unsigned uphi = shr1_dpp(Rhi_);                                      \
        const unsigned long long up = ((unsigned long long)uphi << 32) | uplo;     \
        const unsigned long long mx = (up > kb) ? up : kb;                         \
        const unsigned long long nw = keep ? RP : mx;                              \
        Rhi_ = (unsigned)(nw >> 32);                                               \
        Rlo_ = (unsigned)nw;                                                       \
    }

// Cheap wave-XOR shuffles for the bitonic stages (avoid ds_bpermute):
#define DPPX1(v)  ((unsigned)__builtin_amdgcn_update_dpp(0, (int)(v), 0xB1, 0xF, 0xF, true)) // quad_perm xor1
#define DPPX2(v)  ((unsigned)__builtin_amdgcn_update_dpp(0, (int)(v), 0x4E, 0xF, 0xF, true)) // quad_perm xor2
#define SWZ4(v)   ((unsigned)__builtin_amdgcn_ds_swizzle((int)(v), 0x101F))                  // xor4
#define SWZ8(v)   ((unsigned)__builtin_amdgcn_ds_swizzle((int)(v), 0x201F))                  // xor8
#define SWZ16(v)  ((unsigned)__builtin_amdgcn_ds_swizzle((int)(v), 0x401F))                  // xor16
#define SX32(v)   ((unsigned)__shfl_xor((int)(v), 32, 64))                                   // xor32

// One bitonic compare-exchange stage on u64 keyA/keyB (A/B interleaved, ILP).
#define CE(K, J, SH)                                                         \
    {                                                                        \
        const unsigned pAl = SH((unsigned)keyA);                             \
        const unsigned pAh = SH((unsigned)(keyA >> 32));                     \
        const unsigned pBl = SH((unsigned)keyB);                             \
        const unsigned pBh = SH((unsigned)(keyB >> 32));                     \
        const unsigned long long pA = ((unsigned long long)pAh << 32) | pAl; \
        const unsigned long long pB = ((unsigned long long)pBh << 32) | pBl; \
        const bool up = (lane & (K)) == 0;                                   \
        const bool tk = ((lane & (J)) == 0) == up;                           \
        const bool lA = keyA < pA;                                           \
        const unsigned long long mnA = lA ? keyA : pA;                       \
        const unsigned long long mxA = lA ? pA : keyA;                       \
        keyA = tk ? mnA : mxA;                                               \
        const bool lB = keyB < pB;                                           \
        const unsigned long long mnB = lB ? keyB : pB;                       \
        const unsigned long long mxB = lB ? pB : keyB;                       \
        keyB = tk ? mnB : mxB;                                               \
    }

// ---------------------------------------------------------------------------
// Kernel A: exact KNN (proven R8/R11 v11 body) + prep FOLDED IN as blocks
// >= KNN_BLOCKS (saves one kernel launch + gap). Prep mapping identical to
// the proven prep_kernel, just re-gridded to 10 x 1024 threads.
// ---------------------------------------------------------------------------
__global__ __launch_bounds__(1024, 8) void knn_prep_kernel(
    const float* __restrict__ pos, const float* __restrict__ W2,
    const float* __restrict__ W1, unsigned short* __restrict__ ws,
    float* __restrict__ out)
{
    __shared__ float4 ppos[N_NODES];                 // 64 KB
    __shared__ unsigned long long qual[16][2][64];   // 16 KB -> 80 KB total

    if (blockIdx.x >= KNN_BLOCKS) {
        // ---- prep: W2/W1 bf16 B-fragments into ws (proven mapping) ----
        const int idx = (blockIdx.x - KNN_BLOCKS) * 1024 + threadIdx.x;  // 0..10239
        if (idx < 8192) {
            const int j    = idx & 7;
            const int lane = (idx >> 3) & 63;
            const int kt   = (idx >> 9) & 1;
            const int nt   = idx >> 10;
            const int k = kt * 32 + (lane >> 4) * 8 + j;
            const int n = nt * 16 + (lane & 15);
            ws[idx] = f2bf(W2[k * O_DIM + n]);
        } else if (idx < 8192 + 2048) {
            const int t = idx - 8192;
            const int j    = t & 7;
            const int lane = (t >> 3) & 63;
            const int nt   = t >> 9;          // 0..3
            const int k = (lane >> 4) * 8 + j;          // 0..31
            const int n = nt * 16 + (lane & 15);        // hidden channel
            ws[idx] = (k < 11) ? f2bf(W1[k * H_DIM + n]) : (unsigned short)0;
        }
        return;
    }

    const int b  = blockIdx.x >> 7;           // 128 blocks per cloud
    const int i0 = (blockIdx.x & 127) << 5;   // 32 targets per block
    const float* posb = pos + (size_t)b * N_NODES * 3;

    for (int n = threadIdx.x; n < N_NODES; n += 1024) {
        ppos[n] = make_float4(posb[3 * n], posb[3 * n + 1], posb[3 * n + 2], 0.f);
    }
    __syncthreads();

    const int wave = threadIdx.x >> 6;
    const int lane = threadIdx.x & 63;
    const int iA = i0 + (wave << 1);
    const int iB = iA + 1;

    const float4 pa4 = ppos[iA];
    const float4 pb4 = ppos[iB];
    const float pax = pa4.x, pay = pa4.y, paz = pa4.z;
    const float pbx = pb4.x, pby = pb4.y, pbz = pb4.z;

    // ---- pass 1 (transposed): lane l covers block l; 4 class-mins each ----
    unsigned mA0 = ~0u, mA1 = ~0u, mA2 = ~0u, mA3 = ~0u;
    unsigned mB0 = ~0u, mB1 = ~0u, mB2 = ~0u, mB3 = ~0u;
#pragma unroll 8
    for (int c = 0; c < 64; ++c) {
        const int jj = (lane << 6) | (c ^ lane);   // block l, XOR-staggered
        const float4 p = ppos[jj];
        // bitwise-exact fp32: ((dx*dx + dy*dy) + dz*dz), no FMA contraction
        const float dxA = __fsub_rn(pax, p.x);
        const float dyA = __fsub_rn(pay, p.y);
        const float dzA = __fsub_rn(paz, p.z);
        const float d2A = __fadd_rn(__fadd_rn(__fmul_rn(dxA, dxA), __fmul_rn(dyA, dyA)),
                                    __fmul_rn(dzA, dzA));
        const float dxB = __fsub_rn(pbx, p.x);
        const float dyB = __fsub_rn(pby, p.y);
        const float dzB = __fsub_rn(pbz, p.z);
        const float d2B = __fadd_rn(__fadd_rn(__fmul_rn(dxB, dxB), __fmul_rn(dyB, dyB)),
                                    __fmul_rn(dzB, dzB));
        const unsigned dA = __float_as_uint(d2A);
        const unsigned dB = __float_as_uint(d2B);
        if ((c & 3) == 0)      { mA0 = min(mA0, dA); mB0 = min(mB0, dB); }
        else if ((c & 3) == 1) { mA1 = min(mA1, dA); mB1 = min(mB1, dB); }
        else if ((c & 3) == 2) { mA2 = min(mA2, dA); mB2 = min(mB2, dB); }
        else                   { mA3 = min(mA3, dA); mB3 = min(mB3, dB); }
    }

    // ---- truncated radix-select (A/B interleaved): t >= 40th real dist ----
    unsigned accA = 0, accB = 0;
    for (int bit = 30; bit >= 13; --bit) {
        const unsigned tA = accA | (1u << bit);
        const unsigned tB = accB | (1u << bit);
        const int cA = __popcll(__ballot(mA0 < tA)) + __popcll(__ballot(mA1 < tA))
                     + __popcll(__ballot(mA2 < tA)) + __popcll(__ballot(mA3 < tA));
        const int cB = __popcll(__ballot(mB0 < tB)) + __popcll(__ballot(mB1 < tB))
                     + __popcll(__ballot(mB2 < tB)) + __popcll(__ballot(mB3 < tB));
        if (cA <= K_NN) accA = tA;
        if (cB <= K_NN) accB = tB;
    }
    const unsigned thA = accA | 0x1FFFu;
    const unsigned thB = accB | 0x1FFFu;

    // ---- prune mask: bit l set iff block l holds a qualifier for A or B ----
    const unsigned bmA = min(min(mA0, mA1), min(mA2, mA3));
    const unsigned bmB = min(min(mB0, mB1), min(mB2, mB3));
    unsigned long long sm = __ballot(bmA <= thA) | __ballot(bmB <= thB);
    // self blocks always set (d2=0 <= th), so emit logic below is safe.

    // ---- pass 2: visit only qualifying chunks; branch-free compaction ----
    unsigned long long* qA = qual[wave][0];
    unsigned long long* qB = qual[wave][1];
    int baseA = 0, baseB = 0;
    while (sm) {
        const int c = (int)__builtin_ctzll(sm);
        sm &= sm - 1;
        const float4 p = ppos[(c << 6) | lane];
        const float dxA = __fsub_rn(pax, p.x);
        const float dyA = __fsub_rn(pay, p.y);
        const float dzA = __fsub_rn(paz, p.z);
        const float d2A = __fadd_rn(__fadd_rn(__fmul_rn(dxA, dxA), __fmul_rn(dyA, dyA)),
                                    __fmul_rn(dzA, dzA));
        const float dxB = __fsub_rn(pbx, p.x);
        const float dyB = __fsub_rn(pby, p.y);
        const float dzB = __fsub_rn(pbz, p.z);
        const float d2B = __fadd_rn(__fadd_rn(__fmul_rn(dxB, dxB), __fmul_rn(dyB, dyB)),
                                    __fmul_rn(dzB, dzB));
        const unsigned dA = __float_as_uint(d2A);
        const unsigned dB = __float_as_uint(d2B);
        const unsigned jj = (unsigned)((c << 6) | lane);

        const bool sA = dA <= thA;
        const unsigned long long mkA = __ballot(sA);
        const unsigned mbA = __builtin_amdgcn_mbcnt_hi(
            (unsigned)(mkA >> 32), __builtin_amdgcn_mbcnt_lo((unsigned)mkA, 0u));
        const int idxA = baseA + (int)mbA;
        if (sA && idxA < 64)
            qA[idxA] = ((unsigned long long)dA << 32) | jj;
        baseA += (int)__popcll(mkA);

        const bool sB = dB <= thB;
        const unsigned long long mkB = __ballot(sB);
        const unsigned mbB = __builtin_amdgcn_mbcnt_hi(
            (unsigned)(mkB >> 32), __builtin_amdgcn_mbcnt_lo((unsigned)mkB, 0u));
        const int idxB = baseB + (int)mbB;
        if (sB && idxB < 64)
            qB[idxB] = ((unsigned long long)dB << 32) | jj;
        baseB += (int)__popcll(mkB);
    }

    float* src_out = out + OUT_FEAT_ELEMS;
    float* tgt_out = src_out + EDGES;
    const int giA = b * N_NODES + iA;
    const int giB = giA + 1;

    if (baseA <= 64 && baseB <= 64) {
        // ---- interleaved bitonic, DS-light shuffles (21 stages) ----
        unsigned long long keyA = (lane < baseA) ? qA[lane] : ~0ull;
        unsigned long long keyB = (lane < baseB) ? qB[lane] : ~0ull;
        CE(2, 1, DPPX1)
        CE(4, 2, DPPX2)  CE(4, 1, DPPX1)
        CE(8, 4, SWZ4)   CE(8, 2, DPPX2)  CE(8, 1, DPPX1)
        CE(16, 8, SWZ8)  CE(16, 4, SWZ4)  CE(16, 2, DPPX2) CE(16, 1, DPPX1)
        CE(32, 16, SWZ16) CE(32, 8, SWZ8) CE(32, 4, SWZ4)  CE(32, 2, DPPX2) CE(32, 1, DPPX1)
        CE(64, 32, SX32) CE(64, 16, SWZ16) CE(64, 8, SWZ8) CE(64, 4, SWZ4)  CE(64, 2, DPPX2) CE(64, 1, DPPX1)
        // locate selves (low word == target id; d2=0 always qualifies), emit
        const unsigned loA = (unsigned)keyA;
        const unsigned loB = (unsigned)keyB;
        const int psA = (int)__builtin_ctzll(__ballot(loA == (unsigned)iA));
        const int psB = (int)__builtin_ctzll(__ballot(loB == (unsigned)iB));
        const int elA = lane - (lane > psA ? 1 : 0);
        const int elB = lane - (lane > psB ? 1 : 0);
        if (lane != psA && elA < K_NN) {
            src_out[(size_t)giA * K_NN + elA] = (float)(b * N_NODES + (int)loA);
            tgt_out[(size_t)giA * K_NN + elA] = (float)giA;
        }
        if (lane != psB && elB < K_NN) {
            src_out[(size_t)giB * K_NN + elB] = (float)(b * N_NODES + (int)loB);
            tgt_out[(size_t)giB * K_NN + elB] = (float)giB;
        }
    } else {
        // ---- COLD exact fallback (P~3e-6): full sweep, serial insert ----
        const int ci = iA >> 6;
        const int liA = iA & 63;
        const int liB = iB & 63;
        unsigned RAhi = (lane == 0) ? 0u : 0xFFFFFFFFu;
        unsigned RAlo = (lane == 0) ? 0u : 0xFFFFFFFFu;
        unsigned RBhi = RAhi, RBlo = RAlo;
        for (int c = 0; c < 64; ++c) {
            const float4 p = ppos[(c << 6) | lane];
            const float dxA = __fsub_rn(pax, p.x);
            const float dyA = __fsub_rn(pay, p.y);
            const float dzA = __fsub_rn(paz, p.z);
            const float d2A = __fadd_rn(__fadd_rn(__fmul_rn(dxA, dxA), __fmul_rn(dyA, dyA)),
                                        __fmul_rn(dzA, dzA));
            const float dxB = __fsub_rn(pbx, p.x);
            const float dyB = __fsub_rn(pby, p.y);
            const float dzB = __fsub_rn(pbz, p.z);
            const float d2B = __fadd_rn(__fadd_rn(__fmul_rn(dxB, dxB), __fmul_rn(dyB, dyB)),
                                        __fmul_rn(dzB, dzB));
            const unsigned dA = __float_as_uint(d2A);
            const unsigned dB = __float_as_uint(d2B);
            unsigned long long maskA = __ballot(dA <= thA);
            unsigned long long maskB = __ballot(dB <= thB);
            if (c == ci) {
                maskA &= ~(1ull << liA);
                maskB &= ~(1ull << liB);
            }
            while (maskA) INS_STEP(maskA, dA, RAhi, RAlo);
            while (maskB) INS_STEP(maskB, dB, RBhi, RBlo);
        }
        const unsigned el = (unsigned)(lane - 1);
        if (el < K_NN) {
            src_out[(size_t)giA * K_NN + el] = (float)(b * N_NODES + (int)RAlo);
            tgt_out[(size_t)giA * K_NN + el] = (float)giA;
            src_out[(size_t)giB * K_NN + el] = (float)(b * N_NODES + (int)RBlo);
            tgt_out[(size_t)giB * K_NN + el] = (float)giB;
        }
    }
}

// ---------------------------------------------------------------------------
// Kernel B: per-edge MLP, both layers MFMA — R8 body + R12 epilogue:
// vm kept in statically-indexed regs; bias b2 folded into 2 coalesced loads;
// output written as 2 wave-wide coalesced stores (was: 8x 16-lane stores +
// 8 scalar b2 loads). No runtime register indexing anywhere (rule-20 safe:
// the nt loop is fully unrolled so vmv[nt] is a static index; the final
// select tree uses only static indices with cndmask on lane bits).
// ---------------------------------------------------------------------------
#define HSTR 72   // Hh row stride (bf16): 144 B
#define KSTR 40   // msg row stride (bf16): 80 B, 16B-aligned rows

__global__ __launch_bounds__(256, 5) void conv_kernel(
    const float* __restrict__ x, const float* __restrict__ pos,
    const unsigned short* __restrict__ w2f,   // d_ws: w2 frags [0,8192)
    const unsigned short* __restrict__ w1f,   // d_ws: w1 frags [8192,10240)
    const float* __restrict__ b1, const float* __restrict__ b2,
    float* __restrict__ out)
{
    __shared__ __align__(16) unsigned short Hh[4][48 * HSTR];    // 27648 B

    const int b    = blockIdx.x >> 10;
    const int i0   = (blockIdx.x & 1023) << 2;
    const int wave = threadIdx.x >> 6;
    const int lane = threadIdx.x & 63;
    const int quad = lane >> 4;
    const int col  = lane & 15;
    const int i    = i0 + wave;
    const int gi   = b * N_NODES + i;

    unsigned short* Hw = Hh[wave];

    // ---- phase 1: lane n (<48) gathers message row n, stages bf16 to LDS ----
    const float* src_edges = out + OUT_FEAT_ELEMS;
    if (lane < 48) {
        int j;
        if (lane < K_NN) j = (int)src_edges[(size_t)gi * K_NN + lane] - b * N_NODES;
        else             j = i;   // rows 40..47: self row + pad dups (max-safe)
        const float* xr = x + ((size_t)b * N_NODES + j) * F_IN;
        float4 xa = *(const float4*)xr;
        float4 xb = *(const float4*)(xr + 4);
        const float* pj = pos + ((size_t)b * N_NODES + j) * 3;
        const float* pi = pos + ((size_t)b * N_NODES + i) * 3;
        unsigned w[16];
#pragma unroll
        for (int t = 0; t < 16; ++t) w[t] = 0;
        w[0] = (unsigned)f2bf(xa.x) | ((unsigned)f2bf(xa.y) << 16);
        w[1] = (unsigned)f2bf(xa.z) | ((unsigned)f2bf(xa.w) << 16);
        w[2] = (unsigned)f2bf(xb.x) | ((unsigned)f2bf(xb.y) << 16);
        w[3] = (unsigned)f2bf(xb.z) | ((unsigned)f2bf(xb.w) << 16);
        w[4] = (unsigned)f2bf(pj[0] - pi[0]) | ((unsigned)f2bf(pj[1] - pi[1]) << 16);
        w[5] = (unsigned)f2bf(pj[2] - pi[2]);
        unsigned* mrow = (unsigned*)(Hw + lane * KSTR);
        *(uint4*)(mrow)      = make_uint4(w[0], w[1], w[2], w[3]);
        *(uint4*)(mrow + 4)  = make_uint4(w[4], w[5], w[6], w[7]);
        *(uint4*)(mrow + 8)  = make_uint4(w[8], w[9], w[10], w[11]);
        *(uint4*)(mrow + 12) = make_uint4(w[12], w[13], w[14], w[15]);
    }
    // same-wave ds_write -> ds_read: ordered by lgkmcnt, no barrier needed

    // ---- layer 1 via MFMA: H[48x64] = msg[48x32] . W1[32x64] ----
    bf16x8 Am[3];
#pragma unroll
    for (int mt = 0; mt < 3; ++mt)
        Am[mt] = *(const bf16x8*)&Hw[(mt * 16 + col) * KSTR + quad * 8];

    const bf16x8* W1f = (const bf16x8*)w1f;
    float hreg[12][4];
#pragma unroll
    for (int nt = 0; nt < 4; ++nt) {
        bf16x8 Bn = W1f[nt * 64 + lane];
        const float bias = b1[nt * 16 + col];
        f32x4 d0 = {bias, bias, bias, bias};
        f32x4 d1 = d0, d2 = d0;
        d0 = __builtin_amdgcn_mfma_f32_16x16x32_bf16(Am[0], Bn, d0, 0, 0, 0);
        d1 = __builtin_amdgcn_mfma_f32_16x16x32_bf16(Am[1], Bn, d1, 0, 0, 0);
        d2 = __builtin_amdgcn_mfma_f32_16x16x32_bf16(Am[2], Bn, d2, 0, 0, 0);
#pragma unroll
        for (int r = 0; r < 4; ++r) {
            hreg[nt * 3 + 0][r] = fmaxf(d0[r], 0.0f);
            hreg[nt * 3 + 1][r] = fmaxf(d1[r], 0.0f);
            hreg[nt * 3 + 2][r] = fmaxf(d2[r], 0.0f);
        }
    }

    // msg fully consumed -> overwrite region as Hh[row][hidden]
#pragma unroll
    for (int nt = 0; nt < 4; ++nt)
#pragma unroll
        for (int mt = 0; mt < 3; ++mt)
#pragma unroll
            for (int r = 0; r < 4; ++r)
                Hw[(mt * 16 + quad * 4 + r) * HSTR + nt * 16 + col] =
                    f2bf(hreg[nt * 3 + mt][r]);

    // ---- layer 2 via MFMA ----
    bf16x8 Af[3][2];
#pragma unroll
    for (int mt = 0; mt < 3; ++mt)
#pragma unroll
        for (int kt = 0; kt < 2; ++kt)
            Af[mt][kt] = *(const bf16x8*)&Hw[(mt * 16 + col) * HSTR + kt * 32 + quad * 8];

    const bf16x8* Bws = (const bf16x8*)w2f;
    float vmv[8];
#pragma unroll
    for (int nt = 0; nt < 8; ++nt) {
        bf16x8 B0 = Bws[nt * 128 + lane];
        bf16x8 B1 = Bws[nt * 128 + 64 + lane];

        f32x4 c0 = {0.f, 0.f, 0.f, 0.f};
        f32x4 c1 = {0.f, 0.f, 0.f, 0.f};
        f32x4 c2 = {0.f, 0.f, 0.f, 0.f};
        c0 = __builtin_amdgcn_mfma_f32_16x16x32_bf16(Af[0][0], B0, c0, 0, 0, 0);
        c1 = __builtin_amdgcn_mfma_f32_16x16x32_bf16(Af[1][0], B0, c1, 0, 0, 0);
        c2 = __builtin_amdgcn_mfma_f32_16x16x32_bf16(Af[2][0], B0, c2, 0, 0, 0);
        c0 = __builtin_amdgcn_mfma_f32_16x16x32_bf16(Af[0][1], B1, c0, 0, 0, 0);
        c1 = __builtin_amdgcn_mfma_f32_16x16x32_bf16(Af[1][1], B1, c1, 0, 0, 0);
        c2 = __builtin_amdgcn_mfma_f32_16x16x32_bf16(Af[2][1], B1, c2, 0, 0, 0);

        float vm = c0[0];
        vm = fmaxf(vm, c0[1]); vm = fmaxf(vm, c0[2]); vm = fmaxf(vm, c0[3]);
        vm = fmaxf(vm, c1[0]); vm = fmaxf(vm, c1[1]); vm = fmaxf(vm, c1[2]); vm = fmaxf(vm, c1[3]);
        vm = fmaxf(vm, c2[0]); vm = fmaxf(vm, c2[1]); vm = fmaxf(vm, c2[2]); vm = fmaxf(vm, c2[3]);
        vm = fmaxf(vm, __shfl_xor(vm, 16));
        vm = fmaxf(vm, __shfl_xor(vm, 32));
        vmv[nt] = vm;          // nt compile-time (unrolled) -> stays in regs
    }

    // ---- epilogue: 2 coalesced wave-wide stores; b2 via 2 coalesced loads.
    // store1: channel = lane (nt = lane>>4); store2: channel = 64+lane.
    // vmv[nt] in lane l holds the max for channel nt*16 + (l&15) -> the
    // 3-level static-index select tree picks nt = l>>4 (cndmask on lane bits).
    {
        const float b2a = b2[lane];
        const float b2b = b2[64 + lane];
        const float sA1 = (lane & 16) ? vmv[1] : vmv[0];
        const float sA2 = (lane & 16) ? vmv[3] : vmv[2];
        const float vA  = ((lane & 32) ? sA2 : sA1) + b2a;
        const float sB1 = (lane & 16) ? vmv[5] : vmv[4];
        const float sB2 = (lane & 16) ? vmv[7] : vmv[6];
        const float vB  = ((lane & 32) ? sB2 : sB1) + b2b;
        out[(size_t)gi * O_DIM + lane]      = vA;
        out[(size_t)gi * O_DIM + 64 + lane] = vB;
    }
}

// ---------------------------------------------------------------------------
extern "C" void kernel_launch(void* const* d_in, const int* in_sizes, int n_in,
                              void* d_out, int out_size, void* d_ws, size_t ws_size,
                              hipStream_t stream) {
    const float* x   = (const float*)d_in[0];
    const float* pos = (const float*)d_in[1];
    const float* W1  = (const float*)d_in[2];
    const float* b1  = (const float*)d_in[3];
    const float* W2  = (const float*)d_in[4];
    const float* b2  = (const float*)d_in[5];
    float* out = (float*)d_out;
    unsigned short* ws = (unsigned short*)d_ws;   // 10240 bf16 = 20.5 KB

    knn_prep_kernel<<<KNN_BLOCKS + PREP_BLOCKS, 1024, 0, stream>>>(pos, W2, W1, ws, out);
    conv_kernel<<<(B_CLOUDS * N_NODES) / 4, 256, 0, stream>>>(
        x, pos, ws, ws + 8192, b1, b2, out);
}

// Round 13
// 178.545 us; speedup vs baseline: 1.7154x; 1.0300x over previous
//
#include <hip/hip_runtime.h>
#include <stdint.h>

#define N_NODES 4096
#define K_NN    40
#define B_CLOUDS 8
#define F_IN    8
#define H_DIM   64
#define O_DIM   128

#define OUT_FEAT_ELEMS (B_CLOUDS * N_NODES * O_DIM)   // 4194304
#define EDGES          (B_CLOUDS * N_NODES * K_NN)    // 1310720

#define KNN_BLOCKS 1024
#define PREP_BLOCKS 10   // 10 x 1024 threads covers 10240 prep elements

typedef short bf16x8 __attribute__((ext_vector_type(8)));
typedef float f32x4  __attribute__((ext_vector_type(4)));

__device__ __forceinline__ unsigned short f2bf(float f) {
    unsigned u = __float_as_uint(f);
    unsigned r = (u + 0x7FFFu + ((u >> 16) & 1u)) >> 16;   // RNE
    return (unsigned short)r;
}

// HW packed f32->bf16 RNE: identical rounding to f2bf, 1 inst for 2 values.
__device__ __forceinline__ unsigned cvt_pk_bf16(float lo, float hi) {
    unsigned r;
    asm("v_cvt_pk_bf16_f32 %0, %1, %2" : "=v"(r) : "v"(lo), "v"(hi));
    return r;
}

// wave_shr:1 — lane i receives lane i-1's value (COLD fallback path only).
__device__ __forceinline__ unsigned shr1_dpp(unsigned v) {
    return (unsigned)__builtin_amdgcn_update_dpp(0, (int)v, 0x138, 0xF, 0xF, true);
}

// One sorted-insert step (proven v3/v5 machinery) — COLD fallback only.
#define INS_STEP(mask_, dreg_, Rhi_, Rlo_)                                         \
    {                                                                              \
        const int src = (int)__builtin_ctzll(mask_);                               \
        mask_ &= mask_ - 1;                                                        \
        const unsigned long long kb =                                              \
            ((unsigned long long)(unsigned)__builtin_amdgcn_readlane((int)(dreg_), src) << 32) \
            | (unsigned)((c << 6) | src);                                          \
        const unsigned long long RP = ((unsigned long long)Rhi_ << 32) | Rlo_;     \
        const bool keep = (RP <= kb);                                              \
        const unsigned uplo = shr1_dpp(Rlo_);                                      \
        const unsigned uphi = shr1_dpp(Rhi_);                                      \
        const unsigned long long up = ((unsigned long long)uphi << 32) | uplo;     \
        const unsigned long long mx = (up > kb) ? up : kb;                         \
        const unsigned long long nw = keep ? RP : mx;                              \
        Rhi_ = (unsigned)(nw >> 32);                                               \
        Rlo_ = (unsigned)nw;                                                       \
    }

// Cheap wave-XOR shuffles for the bitonic stages (avoid ds_bpermute):
#define DPPX1(v)  ((unsigned)__builtin_amdgcn_update_dpp(0, (int)(v), 0xB1, 0xF, 0xF, true)) // quad_perm xor1
#define DPPX2(v)  ((unsigned)__builtin_amdgcn_update_dpp(0, (int)(v), 0x4E, 0xF, 0xF, true)) // quad_perm xor2
#define SWZ4(v)   ((unsigned)__builtin_amdgcn_ds_swizzle((int)(v), 0x101F))                  // xor4
#define SWZ8(v)   ((unsigned)__builtin_amdgcn_ds_swizzle((int)(v), 0x201F))                  // xor8
#define SWZ16(v)  ((unsigned)__builtin_amdgcn_ds_swizzle((int)(v), 0x401F))                  // xor16
#define SX32(v)   ((unsigned)__shfl_xor((int)(v), 32, 64))                                   // xor32

// One bitonic compare-exchange stage on u64 keyA/keyB (A/B interleaved, ILP).
#define CE(K, J, SH)                                                         \
    {                                                                        \
        const unsigned pAl = SH((unsigned)keyA);                             \
        const unsigned pAh = SH((unsigned)(keyA >> 32));                     \
        const unsigned pBl = SH((unsigned)keyB);                             \
        const unsigned pBh = SH((unsigned)(keyB >> 32));                     \
        const unsigned long long pA = ((unsigned long long)pAh << 32) | pAl; \
        const unsigned long long pB = ((unsigned long long)pBh << 32) | pBl; \
        const bool up = (lane & (K)) == 0;                                   \
        const bool tk = ((lane & (J)) == 0) == up;                           \
        const bool lA = keyA < pA;                                           \
        const unsigned long long mnA = lA ? keyA : pA;                       \
        const unsigned long long mxA = lA ? pA : keyA;                       \
        keyA = tk ? mnA : mxA;                                               \
        const bool lB = keyB < pB;                                           \
        const unsigned long long mnB = lB ? keyB : pB;                       \
        const unsigned long long mxB = lB ? pB : keyB;                       \
        keyB = tk ? mnB : mxB;                                               \
    }

// ---------------------------------------------------------------------------
// Kernel A: exact KNN (proven R8/R11 v11 body) + prep folded in as blocks
// >= KNN_BLOCKS — UNCHANGED from R12 (proven, 84.1 µs, all gates clean).
// ---------------------------------------------------------------------------
__global__ __launch_bounds__(1024, 8) void knn_prep_kernel(
    const float* __restrict__ pos, const float* __restrict__ W2,
    const float* __restrict__ W1, unsigned short* __restrict__ ws,
    float* __restrict__ out)
{
    __shared__ float4 ppos[N_NODES];                 // 64 KB
    __shared__ unsigned long long qual[16][2][64];   // 16 KB -> 80 KB total

    if (blockIdx.x >= KNN_BLOCKS) {
        // ---- prep: W2/W1 bf16 B-fragments into ws (proven mapping) ----
        const int idx = (blockIdx.x - KNN_BLOCKS) * 1024 + threadIdx.x;  // 0..10239
        if (idx < 8192) {
            const int j    = idx & 7;
            const int lane = (idx >> 3) & 63;
            const int kt   = (idx >> 9) & 1;
            const int nt   = idx >> 10;
            const int k = kt * 32 + (lane >> 4) * 8 + j;
            const int n = nt * 16 + (lane & 15);
            ws[idx] = f2bf(W2[k * O_DIM + n]);
        } else if (idx < 8192 + 2048) {
            const int t = idx - 8192;
            const int j    = t & 7;
            const int lane = (t >> 3) & 63;
            const int nt   = t >> 9;          // 0..3
            const int k = (lane >> 4) * 8 + j;          // 0..31
            const int n = nt * 16 + (lane & 15);        // hidden channel
            ws[idx] = (k < 11) ? f2bf(W1[k * H_DIM + n]) : (unsigned short)0;
        }
        return;
    }

    const int b  = blockIdx.x >> 7;           // 128 blocks per cloud
    const int i0 = (blockIdx.x & 127) << 5;   // 32 targets per block
    const float* posb = pos + (size_t)b * N_NODES * 3;

    for (int n = threadIdx.x; n < N_NODES; n += 1024) {
        ppos[n] = make_float4(posb[3 * n], posb[3 * n + 1], posb[3 * n + 2], 0.f);
    }
    __syncthreads();

    const int wave = threadIdx.x >> 6;
    const int lane = threadIdx.x & 63;
    const int iA = i0 + (wave << 1);
    const int iB = iA + 1;

    const float4 pa4 = ppos[iA];
    const float4 pb4 = ppos[iB];
    const float pax = pa4.x, pay = pa4.y, paz = pa4.z;
    const float pbx = pb4.x, pby = pb4.y, pbz = pb4.z;

    // ---- pass 1 (transposed): lane l covers block l; 4 class-mins each ----
    unsigned mA0 = ~0u, mA1 = ~0u, mA2 = ~0u, mA3 = ~0u;
    unsigned mB0 = ~0u, mB1 = ~0u, mB2 = ~0u, mB3 = ~0u;
#pragma unroll 8
    for (int c = 0; c < 64; ++c) {
        const int jj = (lane << 6) | (c ^ lane);   // block l, XOR-staggered
        const float4 p = ppos[jj];
        // bitwise-exact fp32: ((dx*dx + dy*dy) + dz*dz), no FMA contraction
        const float dxA = __fsub_rn(pax, p.x);
        const float dyA = __fsub_rn(pay, p.y);
        const float dzA = __fsub_rn(paz, p.z);
        const float d2A = __fadd_rn(__fadd_rn(__fmul_rn(dxA, dxA), __fmul_rn(dyA, dyA)),
                                    __fmul_rn(dzA, dzA));
        const float dxB = __fsub_rn(pbx, p.x);
        const float dyB = __fsub_rn(pby, p.y);
        const float dzB = __fsub_rn(pbz, p.z);
        const float d2B = __fadd_rn(__fadd_rn(__fmul_rn(dxB, dxB), __fmul_rn(dyB, dyB)),
                                    __fmul_rn(dzB, dzB));
        const unsigned dA = __float_as_uint(d2A);
        const unsigned dB = __float_as_uint(d2B);
        if ((c & 3) == 0)      { mA0 = min(mA0, dA); mB0 = min(mB0, dB); }
        else if ((c & 3) == 1) { mA1 = min(mA1, dA); mB1 = min(mB1, dB); }
        else if ((c & 3) == 2) { mA2 = min(mA2, dA); mB2 = min(mB2, dB); }
        else                   { mA3 = min(mA3, dA); mB3 = min(mB3, dB); }
    }

    // ---- truncated radix-select (A/B interleaved): t >= 40th real dist ----
    unsigned accA = 0, accB = 0;
    for (int bit = 30; bit >= 13; --bit) {
        const unsigned tA = accA | (1u << bit);
        const unsigned tB = accB | (1u << bit);
        const int cA = __popcll(__ballot(mA0 < tA)) + __popcll(__ballot(mA1 < tA))
                     + __popcll(__ballot(mA2 < tA)) + __popcll(__ballot(mA3 < tA));
        const int cB = __popcll(__ballot(mB0 < tB)) + __popcll(__ballot(mB1 < tB))
                     + __popcll(__ballot(mB2 < tB)) + __popcll(__ballot(mB3 < tB));
        if (cA <= K_NN) accA = tA;
        if (cB <= K_NN) accB = tB;
    }
    const unsigned thA = accA | 0x1FFFu;
    const unsigned thB = accB | 0x1FFFu;

    // ---- prune mask: bit l set iff block l holds a qualifier for A or B ----
    const unsigned bmA = min(min(mA0, mA1), min(mA2, mA3));
    const unsigned bmB = min(min(mB0, mB1), min(mB2, mB3));
    unsigned long long sm = __ballot(bmA <= thA) | __ballot(bmB <= thB);
    // self blocks always set (d2=0 <= th), so emit logic below is safe.

    // ---- pass 2: visit only qualifying chunks; branch-free compaction ----
    unsigned long long* qA = qual[wave][0];
    unsigned long long* qB = qual[wave][1];
    int baseA = 0, baseB = 0;
    while (sm) {
        const int c = (int)__builtin_ctzll(sm);
        sm &= sm - 1;
        const float4 p = ppos[(c << 6) | lane];
        const float dxA = __fsub_rn(pax, p.x);
        const float dyA = __fsub_rn(pay, p.y);
        const float dzA = __fsub_rn(paz, p.z);
        const float d2A = __fadd_rn(__fadd_rn(__fmul_rn(dxA, dxA), __fmul_rn(dyA, dyA)),
                                    __fmul_rn(dzA, dzA));
        const float dxB = __fsub_rn(pbx, p.x);
        const float dyB = __fsub_rn(pby, p.y);
        const float dzB = __fsub_rn(pbz, p.z);
        const float d2B = __fadd_rn(__fadd_rn(__fmul_rn(dxB, dxB), __fmul_rn(dyB, dyB)),
                                    __fmul_rn(dzB, dzB));
        const unsigned dA = __float_as_uint(d2A);
        const unsigned dB = __float_as_uint(d2B);
        const unsigned jj = (unsigned)((c << 6) | lane);

        const bool sA = dA <= thA;
        const unsigned long long mkA = __ballot(sA);
        const unsigned mbA = __builtin_amdgcn_mbcnt_hi(
            (unsigned)(mkA >> 32), __builtin_amdgcn_mbcnt_lo((unsigned)mkA, 0u));
        const int idxA = baseA + (int)mbA;
        if (sA && idxA < 64)
            qA[idxA] = ((unsigned long long)dA << 32) | jj;
        baseA += (int)__popcll(mkA);

        const bool sB = dB <= thB;
        const unsigned long long mkB = __ballot(sB);
        const unsigned mbB = __builtin_amdgcn_mbcnt_hi(
            (unsigned)(mkB >> 32), __builtin_amdgcn_mbcnt_lo((unsigned)mkB, 0u));
        const int idxB = baseB + (int)mbB;
        if (sB && idxB < 64)
            qB[idxB] = ((unsigned long long)dB << 32) | jj;
        baseB += (int)__popcll(mkB);
    }

    float* src_out = out + OUT_FEAT_ELEMS;
    float* tgt_out = src_out + EDGES;
    const int giA = b * N_NODES + iA;
    const int giB = giA + 1;

    if (baseA <= 64 && baseB <= 64) {
        // ---- interleaved bitonic, DS-light shuffles (21 stages) ----
        unsigned long long keyA = (lane < baseA) ? qA[lane] : ~0ull;
        unsigned long long keyB = (lane < baseB) ? qB[lane] : ~0ull;
        CE(2, 1, DPPX1)
        CE(4, 2, DPPX2)  CE(4, 1, DPPX1)
        CE(8, 4, SWZ4)   CE(8, 2, DPPX2)  CE(8, 1, DPPX1)
        CE(16, 8, SWZ8)  CE(16, 4, SWZ4)  CE(16, 2, DPPX2) CE(16, 1, DPPX1)
        CE(32, 16, SWZ16) CE(32, 8, SWZ8) CE(32, 4, SWZ4)  CE(32, 2, DPPX2) CE(32, 1, DPPX1)
        CE(64, 32, SX32) CE(64, 16, SWZ16) CE(64, 8, SWZ8) CE(64, 4, SWZ4)  CE(64, 2, DPPX2) CE(64, 1, DPPX1)
        // locate selves (low word == target id; d2=0 always qualifies), emit
        const unsigned loA = (unsigned)keyA;
        const unsigned loB = (unsigned)keyB;
        const int psA = (int)__builtin_ctzll(__ballot(loA == (unsigned)iA));
        const int psB = (int)__builtin_ctzll(__ballot(loB == (unsigned)iB));
        const int elA = lane - (lane > psA ? 1 : 0);
        const int elB = lane - (lane > psB ? 1 : 0);
        if (lane != psA && elA < K_NN) {
            src_out[(size_t)giA * K_NN + elA] = (float)(b * N_NODES + (int)loA);
            tgt_out[(size_t)giA * K_NN + elA] = (float)giA;
        }
        if (lane != psB && elB < K_NN) {
            src_out[(size_t)giB * K_NN + elB] = (float)(b * N_NODES + (int)loB);
            tgt_out[(size_t)giB * K_NN + elB] = (float)giB;
        }
    } else {
        // ---- COLD exact fallback (P~3e-6): full sweep, serial insert ----
        const int ci = iA >> 6;
        const int liA = iA & 63;
        const int liB = iB & 63;
        unsigned RAhi = (lane == 0) ? 0u : 0xFFFFFFFFu;
        unsigned RAlo = (lane == 0) ? 0u : 0xFFFFFFFFu;
        unsigned RBhi = RAhi, RBlo = RAlo;
        for (int c = 0; c < 64; ++c) {
            const float4 p = ppos[(c << 6) | lane];
            const float dxA = __fsub_rn(pax, p.x);
            const float dyA = __fsub_rn(pay, p.y);
            const float dzA = __fsub_rn(paz, p.z);
            const float d2A = __fadd_rn(__fadd_rn(__fmul_rn(dxA, dxA), __fmul_rn(dyA, dyA)),
                                        __fmul_rn(dzA, dzA));
            const float dxB = __fsub_rn(pbx, p.x);
            const float dyB = __fsub_rn(pby, p.y);
            const float dzB = __fsub_rn(pbz, p.z);
            const float d2B = __fadd_rn(__fadd_rn(__fmul_rn(dxB, dxB), __fmul_rn(dyB, dyB)),
                                        __fmul_rn(dzB, dzB));
            const unsigned dA = __float_as_uint(d2A);
            const unsigned dB = __float_as_uint(d2B);
            unsigned long long maskA = __ballot(dA <= thA);
            unsigned long long maskB = __ballot(dB <= thB);
            if (c == ci) {
                maskA &= ~(1ull << liA);
                maskB &= ~(1ull << liB);
            }
            while (maskA) INS_STEP(maskA, dA, RAhi, RAlo);
            while (maskB) INS_STEP(maskB, dB, RBhi, RBlo);
        }
        const unsigned el = (unsigned)(lane - 1);
        if (el < K_NN) {
            src_out[(size_t)giA * K_NN + el] = (float)(b * N_NODES + (int)RAlo);
            tgt_out[(size_t)giA * K_NN + el] = (float)giA;
            src_out[(size_t)giB * K_NN + el] = (float)(b * N_NODES + (int)RBlo);
            tgt_out[(size_t)giB * K_NN + el] = (float)giB;
        }
    }
}

// ---------------------------------------------------------------------------
// Kernel B: per-edge MLP, both layers MFMA — R12 body + R13 VALU trim:
//   * msg staging packed via v_cvt_pk_bf16_f32 (1 inst / 2 values, same RNE)
//   * H-store: 2 cvt_pk per (nt,mt) + b16 low/high writes (>>16 folds to
//     ds_write_b16_d16_hi) — replaces 16 VALU of manual f2bf per (nt,mt)
//   * epilogue reduce shaped for v_max3_f32 fusion
// All indices static (rule-20 safe). Epilogue/coalesced stores from R12.
// ---------------------------------------------------------------------------
#define HSTR 72   // Hh row stride (bf16): 144 B
#define KSTR 40   // msg row stride (bf16): 80 B, 16B-aligned rows

__global__ __launch_bounds__(256, 5) void conv_kernel(
    const float* __restrict__ x, const float* __restrict__ pos,
    const unsigned short* __restrict__ w2f,   // d_ws: w2 frags [0,8192)
    const unsigned short* __restrict__ w1f,   // d_ws: w1 frags [8192,10240)
    const float* __restrict__ b1, const float* __restrict__ b2,
    float* __restrict__ out)
{
    __shared__ __align__(16) unsigned short Hh[4][48 * HSTR];    // 27648 B

    const int b    = blockIdx.x >> 10;
    const int i0   = (blockIdx.x & 1023) << 2;
    const int wave = threadIdx.x >> 6;
    const int lane = threadIdx.x & 63;
    const int quad = lane >> 4;
    const int col  = lane & 15;
    const int i    = i0 + wave;
    const int gi   = b * N_NODES + i;

    unsigned short* Hw = Hh[wave];

    // ---- phase 1: lane n (<48) gathers message row n, stages bf16 to LDS ----
    const float* src_edges = out + OUT_FEAT_ELEMS;
    if (lane < 48) {
        int j;
        if (lane < K_NN) j = (int)src_edges[(size_t)gi * K_NN + lane] - b * N_NODES;
        else             j = i;   // rows 40..47: self row + pad dups (max-safe)
        const float* xr = x + ((size_t)b * N_NODES + j) * F_IN;
        float4 xa = *(const float4*)xr;
        float4 xb = *(const float4*)(xr + 4);
        const float* pj = pos + ((size_t)b * N_NODES + j) * 3;
        const float* pi = pos + ((size_t)b * N_NODES + i) * 3;
        unsigned w0 = cvt_pk_bf16(xa.x, xa.y);
        unsigned w1 = cvt_pk_bf16(xa.z, xa.w);
        unsigned w2 = cvt_pk_bf16(xb.x, xb.y);
        unsigned w3 = cvt_pk_bf16(xb.z, xb.w);
        unsigned w4 = cvt_pk_bf16(pj[0] - pi[0], pj[1] - pi[1]);
        unsigned w5 = cvt_pk_bf16(pj[2] - pi[2], 0.0f);
        unsigned* mrow = (unsigned*)(Hw + lane * KSTR);
        *(uint4*)(mrow)      = make_uint4(w0, w1, w2, w3);
        *(uint4*)(mrow + 4)  = make_uint4(w4, w5, 0u, 0u);
        *(uint4*)(mrow + 8)  = make_uint4(0u, 0u, 0u, 0u);
        *(uint4*)(mrow + 12) = make_uint4(0u, 0u, 0u, 0u);
    }
    // same-wave ds_write -> ds_read: ordered by lgkmcnt, no barrier needed

    // ---- layer 1 via MFMA: H[48x64] = msg[48x32] . W1[32x64] ----
    bf16x8 Am[3];
#pragma unroll
    for (int mt = 0; mt < 3; ++mt)
        Am[mt] = *(const bf16x8*)&Hw[(mt * 16 + col) * KSTR + quad * 8];

    const bf16x8* W1f = (const bf16x8*)w1f;
    float hreg[12][4];
#pragma unroll
    for (int nt = 0; nt < 4; ++nt) {
        bf16x8 Bn = W1f[nt * 64 + lane];
        const float bias = b1[nt * 16 + col];
        f32x4 d0 = {bias, bias, bias, bias};
        f32x4 d1 = d0, d2 = d0;
        d0 = __builtin_amdgcn_mfma_f32_16x16x32_bf16(Am[0], Bn, d0, 0, 0, 0);
        d1 = __builtin_amdgcn_mfma_f32_16x16x32_bf16(Am[1], Bn, d1, 0, 0, 0);
        d2 = __builtin_amdgcn_mfma_f32_16x16x32_bf16(Am[2], Bn, d2, 0, 0, 0);
#pragma unroll
        for (int r = 0; r < 4; ++r) {
            hreg[nt * 3 + 0][r] = fmaxf(d0[r], 0.0f);
            hreg[nt * 3 + 1][r] = fmaxf(d1[r], 0.0f);
            hreg[nt * 3 + 2][r] = fmaxf(d2[r], 0.0f);
        }
    }

    // msg fully consumed -> overwrite region as Hh[row][hidden].
    // 2 cvt_pk per (nt,mt); >>16 write folds to ds_write_b16_d16_hi.
#pragma unroll
    for (int nt = 0; nt < 4; ++nt)
#pragma unroll
        for (int mt = 0; mt < 3; ++mt) {
            const unsigned p01 = cvt_pk_bf16(hreg[nt * 3 + mt][0], hreg[nt * 3 + mt][1]);
            const unsigned p23 = cvt_pk_bf16(hreg[nt * 3 + mt][2], hreg[nt * 3 + mt][3]);
            unsigned short* hb = &Hw[(mt * 16 + quad * 4) * HSTR + nt * 16 + col];
            hb[0 * HSTR] = (unsigned short)p01;
            hb[1 * HSTR] = (unsigned short)(p01 >> 16);
            hb[2 * HSTR] = (unsigned short)p23;
            hb[3 * HSTR] = (unsigned short)(p23 >> 16);
        }

    // ---- layer 2 via MFMA ----
    bf16x8 Af[3][2];
#pragma unroll
    for (int mt = 0; mt < 3; ++mt)
#pragma unroll
        for (int kt = 0; kt < 2; ++kt)
            Af[mt][kt] = *(const bf16x8*)&Hw[(mt * 16 + col) * HSTR + kt * 32 + quad * 8];

    const bf16x8* Bws = (const bf16x8*)w2f;
    float vmv[8];
#pragma unroll
    for (int nt = 0; nt < 8; ++nt) {
        bf16x8 B0 = Bws[nt * 128 + lane];
        bf16x8 B1 = Bws[nt * 128 + 64 + lane];

        f32x4 c0 = {0.f, 0.f, 0.f, 0.f};
        f32x4 c1 = {0.f, 0.f, 0.f, 0.f};
        f32x4 c2 = {0.f, 0.f, 0.f, 0.f};
        c0 = __builtin_amdgcn_mfma_f32_16x16x32_bf16(Af[0][0], B0, c0, 0, 0, 0);
        c1 = __builtin_amdgcn_mfma_f32_16x16x32_bf16(Af[1][0], B0, c1, 0, 0, 0);
        c2 = __builtin_amdgcn_mfma_f32_16x16x32_bf16(Af[2][0], B0, c2, 0, 0, 0);
        c0 = __builtin_amdgcn_mfma_f32_16x16x32_bf16(Af[0][1], B1, c0, 0, 0, 0);
        c1 = __builtin_amdgcn_mfma_f32_16x16x32_bf16(Af[1][1], B1, c1, 0, 0, 0);
        c2 = __builtin_amdgcn_mfma_f32_16x16x32_bf16(Af[2][1], B1, c2, 0, 0, 0);

        // balanced reduce (v_max3_f32-shaped: fmax(fmax(a,b),c) fuses)
        const float m0 = fmaxf(fmaxf(c0[0], c0[1]), c0[2]);
        const float m1 = fmaxf(fmaxf(c0[3], c1[0]), c1[1]);
        const float m2 = fmaxf(fmaxf(c1[2], c1[3]), c2[0]);
        const float m3 = fmaxf(fmaxf(c2[1], c2[2]), c2[3]);
        float vm = fmaxf(fmaxf(fmaxf(m0, m1), m2), m3);
        vm = fmaxf(vm, __shfl_xor(vm, 16));
        vm = fmaxf(vm, __shfl_xor(vm, 32));
        vmv[nt] = vm;          // nt compile-time (unrolled) -> stays in regs
    }

    // ---- epilogue: 2 coalesced wave-wide stores; b2 via 2 coalesced loads.
    {
        const float b2a = b2[lane];
        const float b2b = b2[64 + lane];
        const float sA1 = (lane & 16) ? vmv[1] : vmv[0];
        const float sA2 = (lane & 16) ? vmv[3] : vmv[2];
        const float vA  = ((lane & 32) ? sA2 : sA1) + b2a;
        const float sB1 = (lane & 16) ? vmv[5] : vmv[4];
        const float sB2 = (lane & 16) ? vmv[7] : vmv[6];
        const float vB  = ((lane & 32) ? sB2 : sB1) + b2b;
        out[(size_t)gi * O_DIM + lane]      = vA;
        out[(size_t)gi * O_DIM + 64 + lane] = vB;
    }
}

// ---------------------------------------------------------------------------
extern "C" void kernel_launch(void* const* d_in, const int* in_sizes, int n_in,
                              void* d_out, int out_size, void* d_ws, size_t ws_size,
                              hipStream_t stream) {
    const float* x   = (const float*)d_in[0];
    const float* pos = (const float*)d_in[1];
    const float* W1  = (const float*)d_in[2];
    const float* b1  = (const float*)d_in[3];
    const float* W2  = (const float*)d_in[4];
    const float* b2  = (const float*)d_in[5];
    float* out = (float*)d_out;
    unsigned short* ws = (unsigned short*)d_ws;   // 10240 bf16 = 20.5 KB

    knn_prep_kernel<<<KNN_BLOCKS + PREP_BLOCKS, 1024, 0, stream>>>(pos, W2, W1, ws, out);
    conv_kernel<<<(B_CLOUDS * N_NODES) / 4, 256, 0, stream>>>(
        x, pos, ws, ws + 8192, b1, b2, out);
}

// Round 14
// 175.908 us; speedup vs baseline: 1.7411x; 1.0150x over previous
//
#include <hip/hip_runtime.h>
#include <stdint.h>

#define N_NODES 4096
#define K_NN    40
#define B_CLOUDS 8
#define F_IN    8
#define H_DIM   64
#define O_DIM   128

#define OUT_FEAT_ELEMS (B_CLOUDS * N_NODES * O_DIM)   // 4194304
#define EDGES          (B_CLOUDS * N_NODES * K_NN)    // 1310720

#define KNN_BLOCKS 1024
// ws layout (unsigned short base):
//   [0,8192)        w2 frags
//   [8192,10240)    w1 frags
//   [10240,272384)  xbf: 32768 rows x 8 bf16 (16 B/row)
//   [272384,...)    pos4: 32768 x float4 (as float*)  -> total 1069056 B
#define WS_XBF_OFF   10240
#define WS_POS4_OFF  272384          // in shorts; byte 544768, 16B-aligned
#define WS_NEED_B    1069056u

typedef short bf16x8 __attribute__((ext_vector_type(8)));
typedef float f32x4  __attribute__((ext_vector_type(4)));

__device__ __forceinline__ unsigned short f2bf(float f) {
    unsigned u = __float_as_uint(f);
    unsigned r = (u + 0x7FFFu + ((u >> 16) & 1u)) >> 16;   // RNE
    return (unsigned short)r;
}

// HW packed f32->bf16 RNE: identical rounding to f2bf, 1 inst for 2 values.
__device__ __forceinline__ unsigned cvt_pk_bf16(float lo, float hi) {
    unsigned r;
    asm("v_cvt_pk_bf16_f32 %0, %1, %2" : "=v"(r) : "v"(lo), "v"(hi));
    return r;
}

// wave_shr:1 — lane i receives lane i-1's value (COLD fallback path only).
__device__ __forceinline__ unsigned shr1_dpp(unsigned v) {
    return (unsigned)__builtin_amdgcn_update_dpp(0, (int)v, 0x138, 0xF, 0xF, true);
}

// One sorted-insert step (proven v3/v5 machinery) — COLD fallback only.
#define INS_STEP(mask_, dreg_, Rhi_, Rlo_)                                         \
    {                                                                              \
        const int src = (int)__builtin_ctzll(mask_);                               \
        mask_ &= mask_ - 1;                                                        \
        const unsigned long long kb =                                              \
            ((unsigned long long)(unsigned)__builtin_amdgcn_readlane((int)(dreg_), src) << 32) \
            | (unsigned)((c << 6) | src);                                          \
        const unsigned long long RP = ((unsigned long long)Rhi_ << 32) | Rlo_;     \
        const bool keep = (RP <= kb);                                              \
        const unsigned uplo = shr1_dpp(Rlo_);                                      \
        const unsigned uphi = shr1_dpp(Rhi_);                                      \
        const unsigned long long up = ((unsigned long long)uphi << 32) | uplo;     \
        const unsigned long long mx = (up > kb) ? up : kb;                         \
        const unsigned long long nw = keep ? RP : mx;                              \
        Rhi_ = (unsigned)(nw >> 32);                                               \
        Rlo_ = (unsigned)nw;                                                       \
    }

// Cheap wave-XOR shuffles for the bitonic stages (avoid ds_bpermute):
#define DPPX1(v)  ((unsigned)__builtin_amdgcn_update_dpp(0, (int)(v), 0xB1, 0xF, 0xF, true)) // quad_perm xor1
#define DPPX2(v)  ((unsigned)__builtin_amdgcn_update_dpp(0, (int)(v), 0x4E, 0xF, 0xF, true)) // quad_perm xor2
#define SWZ4(v)   ((unsigned)__builtin_amdgcn_ds_swizzle((int)(v), 0x101F))                  // xor4
#define SWZ8(v)   ((unsigned)__builtin_amdgcn_ds_swizzle((int)(v), 0x201F))                  // xor8
#define SWZ16(v)  ((unsigned)__builtin_amdgcn_ds_swizzle((int)(v), 0x401F))                  // xor16
#define SX32(v)   ((unsigned)__shfl_xor((int)(v), 32, 64))                                   // xor32

// One bitonic compare-exchange stage on u64 keyA/keyB (A/B interleaved, ILP).
#define CE(K, J, SH)                                                         \
    {                                                                        \
        const unsigned pAl = SH((unsigned)keyA);                             \
        const unsigned pAh = SH((unsigned)(keyA >> 32));                     \
        const unsigned pBl = SH((unsigned)keyB);                             \
        const unsigned pBh = SH((unsigned)(keyB >> 32));                     \
        const unsigned long long pA = ((unsigned long long)pAh << 32) | pAl; \
        const unsigned long long pB = ((unsigned long long)pBh << 32) | pBl; \
        const bool up = (lane & (K)) == 0;                                   \
        const bool tk = ((lane & (J)) == 0) == up;                           \
        const bool lA = keyA < pA;                                           \
        const unsigned long long mnA = lA ? keyA : pA;                       \
        const unsigned long long mxA = lA ? pA : keyA;                       \
        keyA = tk ? mnA : mxA;                                               \
        const bool lB = keyB < pB;                                           \
        const unsigned long long mnB = lB ? keyB : pB;                       \
        const unsigned long long mxB = lB ? pB : keyB;                       \
        keyB = tk ? mnB : mxB;                                               \
    }

// ---------------------------------------------------------------------------
// Kernel A: exact KNN (proven R8/R11 v11 body) + prep folded in as blocks
// >= KNN_BLOCKS. R14 adds prep blocks that pre-convert x -> bf16 rows and
// pos -> float4 into ws (gated by do_pre, ws_size checked host-side).
// ---------------------------------------------------------------------------
__global__ __launch_bounds__(1024, 8) void knn_prep_kernel(
    const float* __restrict__ pos, const float* __restrict__ W2,
    const float* __restrict__ W1, const float* __restrict__ x,
    unsigned short* __restrict__ ws, float* __restrict__ out)
{
    __shared__ float4 ppos[N_NODES];                 // 64 KB
    __shared__ unsigned long long qual[16][2][64];   // 16 KB -> 80 KB total

    if (blockIdx.x >= KNN_BLOCKS) {
        const int pb = blockIdx.x - KNN_BLOCKS;
        if (pb < 10) {
            // ---- prep: W2/W1 bf16 B-fragments into ws (proven mapping) ----
            const int idx = pb * 1024 + threadIdx.x;   // 0..10239
            if (idx < 8192) {
                const int j    = idx & 7;
                const int lane = (idx >> 3) & 63;
                const int kt   = (idx >> 9) & 1;
                const int nt   = idx >> 10;
                const int k = kt * 32 + (lane >> 4) * 8 + j;
                const int n = nt * 16 + (lane & 15);
                ws[idx] = f2bf(W2[k * O_DIM + n]);
            } else if (idx < 8192 + 2048) {
                const int t = idx - 8192;
                const int j    = t & 7;
                const int lane = (t >> 3) & 63;
                const int nt   = t >> 9;          // 0..3
                const int k = (lane >> 4) * 8 + j;          // 0..31
                const int n = nt * 16 + (lane & 15);        // hidden channel
                ws[idx] = (k < 11) ? f2bf(W1[k * H_DIM + n]) : (unsigned short)0;
            }
        } else if (pb < 42) {
            // ---- prep: x rows -> bf16x8 (RNE identical to per-edge cvt) ----
            const int row = (pb - 10) * 1024 + threadIdx.x;  // 0..32767
            const float4 a  = *(const float4*)(x + (size_t)row * 8);
            const float4 bq = *(const float4*)(x + (size_t)row * 8 + 4);
            uint4 wv;
            wv.x = cvt_pk_bf16(a.x, a.y);
            wv.y = cvt_pk_bf16(a.z, a.w);
            wv.z = cvt_pk_bf16(bq.x, bq.y);
            wv.w = cvt_pk_bf16(bq.z, bq.w);
            *(uint4*)(ws + WS_XBF_OFF + (size_t)row * 8) = wv;
        } else {
            // ---- prep: pos rows -> float4-padded (16 B aligned gather) ----
            const int row = (pb - 42) * 1024 + threadIdx.x;  // 0..32767
            float* pos4 = (float*)(ws + WS_POS4_OFF);
            const float* pr = pos + (size_t)row * 3;
            *(float4*)(pos4 + (size_t)row * 4) = make_float4(pr[0], pr[1], pr[2], 0.f);
        }
        return;
    }

    const int b  = blockIdx.x >> 7;           // 128 blocks per cloud
    const int i0 = (blockIdx.x & 127) << 5;   // 32 targets per block
    const float* posb = pos + (size_t)b * N_NODES * 3;

    for (int n = threadIdx.x; n < N_NODES; n += 1024) {
        ppos[n] = make_float4(posb[3 * n], posb[3 * n + 1], posb[3 * n + 2], 0.f);
    }
    __syncthreads();

    const int wave = threadIdx.x >> 6;
    const int lane = threadIdx.x & 63;
    const int iA = i0 + (wave << 1);
    const int iB = iA + 1;

    const float4 pa4 = ppos[iA];
    const float4 pb4 = ppos[iB];
    const float pax = pa4.x, pay = pa4.y, paz = pa4.z;
    const float pbx = pb4.x, pby = pb4.y, pbz = pb4.z;

    // ---- pass 1 (transposed): lane l covers block l; 4 class-mins each ----
    unsigned mA0 = ~0u, mA1 = ~0u, mA2 = ~0u, mA3 = ~0u;
    unsigned mB0 = ~0u, mB1 = ~0u, mB2 = ~0u, mB3 = ~0u;
#pragma unroll 8
    for (int c = 0; c < 64; ++c) {
        const int jj = (lane << 6) | (c ^ lane);   // block l, XOR-staggered
        const float4 p = ppos[jj];
        // bitwise-exact fp32: ((dx*dx + dy*dy) + dz*dz), no FMA contraction
        const float dxA = __fsub_rn(pax, p.x);
        const float dyA = __fsub_rn(pay, p.y);
        const float dzA = __fsub_rn(paz, p.z);
        const float d2A = __fadd_rn(__fadd_rn(__fmul_rn(dxA, dxA), __fmul_rn(dyA, dyA)),
                                    __fmul_rn(dzA, dzA));
        const float dxB = __fsub_rn(pbx, p.x);
        const float dyB = __fsub_rn(pby, p.y);
        const float dzB = __fsub_rn(pbz, p.z);
        const float d2B = __fadd_rn(__fadd_rn(__fmul_rn(dxB, dxB), __fmul_rn(dyB, dyB)),
                                    __fmul_rn(dzB, dzB));
        const unsigned dA = __float_as_uint(d2A);
        const unsigned dB = __float_as_uint(d2B);
        if ((c & 3) == 0)      { mA0 = min(mA0, dA); mB0 = min(mB0, dB); }
        else if ((c & 3) == 1) { mA1 = min(mA1, dA); mB1 = min(mB1, dB); }
        else if ((c & 3) == 2) { mA2 = min(mA2, dA); mB2 = min(mB2, dB); }
        else                   { mA3 = min(mA3, dA); mB3 = min(mB3, dB); }
    }

    // ---- truncated radix-select (A/B interleaved): t >= 40th real dist ----
    unsigned accA = 0, accB = 0;
    for (int bit = 30; bit >= 13; --bit) {
        const unsigned tA = accA | (1u << bit);
        const unsigned tB = accB | (1u << bit);
        const int cA = __popcll(__ballot(mA0 < tA)) + __popcll(__ballot(mA1 < tA))
                     + __popcll(__ballot(mA2 < tA)) + __popcll(__ballot(mA3 < tA));
        const int cB = __popcll(__ballot(mB0 < tB)) + __popcll(__ballot(mB1 < tB))
                     + __popcll(__ballot(mB2 < tB)) + __popcll(__ballot(mB3 < tB));
        if (cA <= K_NN) accA = tA;
        if (cB <= K_NN) accB = tB;
    }
    const unsigned thA = accA | 0x1FFFu;
    const unsigned thB = accB | 0x1FFFu;

    // ---- prune mask: bit l set iff block l holds a qualifier for A or B ----
    const unsigned bmA = min(min(mA0, mA1), min(mA2, mA3));
    const unsigned bmB = min(min(mB0, mB1), min(mB2, mB3));
    unsigned long long sm = __ballot(bmA <= thA) | __ballot(bmB <= thB);
    // self blocks always set (d2=0 <= th), so emit logic below is safe.

    // ---- pass 2: visit only qualifying chunks; branch-free compaction ----
    unsigned long long* qA = qual[wave][0];
    unsigned long long* qB = qual[wave][1];
    int baseA = 0, baseB = 0;
    while (sm) {
        const int c = (int)__builtin_ctzll(sm);
        sm &= sm - 1;
        const float4 p = ppos[(c << 6) | lane];
        const float dxA = __fsub_rn(pax, p.x);
        const float dyA = __fsub_rn(pay, p.y);
        const float dzA = __fsub_rn(paz, p.z);
        const float d2A = __fadd_rn(__fadd_rn(__fmul_rn(dxA, dxA), __fmul_rn(dyA, dyA)),
                                    __fmul_rn(dzA, dzA));
        const float dxB = __fsub_rn(pbx, p.x);
        const float dyB = __fsub_rn(pby, p.y);
        const float dzB = __fsub_rn(pbz, p.z);
        const float d2B = __fadd_rn(__fadd_rn(__fmul_rn(dxB, dxB), __fmul_rn(dyB, dyB)),
                                    __fmul_rn(dzB, dzB));
        const unsigned dA = __float_as_uint(d2A);
        const unsigned dB = __float_as_uint(d2B);
        const unsigned jj = (unsigned)((c << 6) | lane);

        const bool sA = dA <= thA;
        const unsigned long long mkA = __ballot(sA);
        const unsigned mbA = __builtin_amdgcn_mbcnt_hi(
            (unsigned)(mkA >> 32), __builtin_amdgcn_mbcnt_lo((unsigned)mkA, 0u));
        const int idxA = baseA + (int)mbA;
        if (sA && idxA < 64)
            qA[idxA] = ((unsigned long long)dA << 32) | jj;
        baseA += (int)__popcll(mkA);

        const bool sB = dB <= thB;
        const unsigned long long mkB = __ballot(sB);
        const unsigned mbB = __builtin_amdgcn_mbcnt_hi(
            (unsigned)(mkB >> 32), __builtin_amdgcn_mbcnt_lo((unsigned)mkB, 0u));
        const int idxB = baseB + (int)mbB;
        if (sB && idxB < 64)
            qB[idxB] = ((unsigned long long)dB << 32) | jj;
        baseB += (int)__popcll(mkB);
    }

    float* src_out = out + OUT_FEAT_ELEMS;
    float* tgt_out = src_out + EDGES;
    const int giA = b * N_NODES + iA;
    const int giB = giA + 1;

    if (baseA <= 64 && baseB <= 64) {
        // ---- interleaved bitonic, DS-light shuffles (21 stages) ----
        unsigned long long keyA = (lane < baseA) ? qA[lane] : ~0ull;
        unsigned long long keyB = (lane < baseB) ? qB[lane] : ~0ull;
        CE(2, 1, DPPX1)
        CE(4, 2, DPPX2)  CE(4, 1, DPPX1)
        CE(8, 4, SWZ4)   CE(8, 2, DPPX2)  CE(8, 1, DPPX1)
        CE(16, 8, SWZ8)  CE(16, 4, SWZ4)  CE(16, 2, DPPX2) CE(16, 1, DPPX1)
        CE(32, 16, SWZ16) CE(32, 8, SWZ8) CE(32, 4, SWZ4)  CE(32, 2, DPPX2) CE(32, 1, DPPX1)
        CE(64, 32, SX32) CE(64, 16, SWZ16) CE(64, 8, SWZ8) CE(64, 4, SWZ4)  CE(64, 2, DPPX2) CE(64, 1, DPPX1)
        // locate selves (low word == target id; d2=0 always qualifies), emit
        const unsigned loA = (unsigned)keyA;
        const unsigned loB = (unsigned)keyB;
        const int psA = (int)__builtin_ctzll(__ballot(loA == (unsigned)iA));
        const int psB = (int)__builtin_ctzll(__ballot(loB == (unsigned)iB));
        const int elA = lane - (lane > psA ? 1 : 0);
        const int elB = lane - (lane > psB ? 1 : 0);
        if (lane != psA && elA < K_NN) {
            src_out[(size_t)giA * K_NN + elA] = (float)(b * N_NODES + (int)loA);
            tgt_out[(size_t)giA * K_NN + elA] = (float)giA;
        }
        if (lane != psB && elB < K_NN) {
            src_out[(size_t)giB * K_NN + elB] = (float)(b * N_NODES + (int)loB);
            tgt_out[(size_t)giB * K_NN + elB] = (float)giB;
        }
    } else {
        // ---- COLD exact fallback (P~3e-6): full sweep, serial insert ----
        const int ci = iA >> 6;
        const int liA = iA & 63;
        const int liB = iB & 63;
        unsigned RAhi = (lane == 0) ? 0u : 0xFFFFFFFFu;
        unsigned RAlo = (lane == 0) ? 0u : 0xFFFFFFFFu;
        unsigned RBhi = RAhi, RBlo = RAlo;
        for (int c = 0; c < 64; ++c) {
            const float4 p = ppos[(c << 6) | lane];
            const float dxA = __fsub_rn(pax, p.x);
            const float dyA = __fsub_rn(pay, p.y);
            const float dzA = __fsub_rn(paz, p.z);
            const float d2A = __fadd_rn(__fadd_rn(__fmul_rn(dxA, dxA), __fmul_rn(dyA, dyA)),
                                        __fmul_rn(dzA, dzA));
            const float dxB = __fsub_rn(pbx, p.x);
            const float dyB = __fsub_rn(pby, p.y);
            const float dzB = __fsub_rn(pbz, p.z);
            const float d2B = __fadd_rn(__fadd_rn(__fmul_rn(dxB, dxB), __fmul_rn(dyB, dyB)),
                                        __fmul_rn(dzB, dzB));
            const unsigned dA = __float_as_uint(d2A);
            const unsigned dB = __float_as_uint(d2B);
            unsigned long long maskA = __ballot(dA <= thA);
            unsigned long long maskB = __ballot(dB <= thB);
            if (c == ci) {
                maskA &= ~(1ull << liA);
                maskB &= ~(1ull << liB);
            }
            while (maskA) INS_STEP(maskA, dA, RAhi, RAlo);
            while (maskB) INS_STEP(maskB, dB, RBhi, RBlo);
        }
        const unsigned el = (unsigned)(lane - 1);
        if (el < K_NN) {
            src_out[(size_t)giA * K_NN + el] = (float)(b * N_NODES + (int)RAlo);
            tgt_out[(size_t)giA * K_NN + el] = (float)giA;
            src_out[(size_t)giB * K_NN + el] = (float)(b * N_NODES + (int)RBlo);
            tgt_out[(size_t)giB * K_NN + el] = (float)giB;
        }
    }
}

// ---------------------------------------------------------------------------
// Kernel B: per-edge MLP, both layers MFMA — R13 body; R14: PRE path gathers
// preconverted bf16 x rows (1 dwordx4) + float4 pos (2 dwordx4, pi uniform)
// instead of 9 scattered VMEM ops. PRE=0 = proven R13 legacy (ws too small).
// ---------------------------------------------------------------------------
#define HSTR 72   // Hh row stride (bf16): 144 B
#define KSTR 40   // msg row stride (bf16): 80 B, 16B-aligned rows

template<int PRE>
__global__ __launch_bounds__(256, 5) void conv_kernel(
    const float* __restrict__ x, const float* __restrict__ pos,
    const unsigned short* __restrict__ w2f,   // d_ws: w2 frags [0,8192)
    const unsigned short* __restrict__ w1f,   // d_ws: w1 frags [8192,10240)
    const unsigned short* __restrict__ xbf,   // d_ws: bf16 x rows
    const float* __restrict__ pos4,           // d_ws: float4 pos rows
    const float* __restrict__ b1, const float* __restrict__ b2,
    float* __restrict__ out)
{
    __shared__ __align__(16) unsigned short Hh[4][48 * HSTR];    // 27648 B

    const int b    = blockIdx.x >> 10;
    const int i0   = (blockIdx.x & 1023) << 2;
    const int wave = threadIdx.x >> 6;
    const int lane = threadIdx.x & 63;
    const int quad = lane >> 4;
    const int col  = lane & 15;
    const int i    = i0 + wave;
    const int gi   = b * N_NODES + i;

    unsigned short* Hw = Hh[wave];

    // ---- phase 1: lane n (<48) gathers message row n, stages bf16 to LDS ----
    const float* src_edges = out + OUT_FEAT_ELEMS;
    if (lane < 48) {
        int j;
        if (lane < K_NN) j = (int)src_edges[(size_t)gi * K_NN + lane] - b * N_NODES;
        else             j = i;   // rows 40..47: self row + pad dups (max-safe)
        unsigned w0, w1, w2, w3, w4, w5;
        if (PRE) {
            const uint4 xw = *(const uint4*)(xbf + ((size_t)(b * N_NODES + j)) * 8);
            const float4 pj = *(const float4*)(pos4 + ((size_t)(b * N_NODES + j)) * 4);
            const float4 pi = *(const float4*)(pos4 + ((size_t)(b * N_NODES + i)) * 4);
            w0 = xw.x; w1 = xw.y; w2 = xw.z; w3 = xw.w;
            w4 = cvt_pk_bf16(pj.x - pi.x, pj.y - pi.y);
            w5 = cvt_pk_bf16(pj.z - pi.z, 0.0f);
        } else {
            const float* xr = x + ((size_t)b * N_NODES + j) * F_IN;
            float4 xa = *(const float4*)xr;
            float4 xb = *(const float4*)(xr + 4);
            const float* pj = pos + ((size_t)b * N_NODES + j) * 3;
            const float* pi = pos + ((size_t)b * N_NODES + i) * 3;
            w0 = cvt_pk_bf16(xa.x, xa.y);
            w1 = cvt_pk_bf16(xa.z, xa.w);
            w2 = cvt_pk_bf16(xb.x, xb.y);
            w3 = cvt_pk_bf16(xb.z, xb.w);
            w4 = cvt_pk_bf16(pj[0] - pi[0], pj[1] - pi[1]);
            w5 = cvt_pk_bf16(pj[2] - pi[2], 0.0f);
        }
        unsigned* mrow = (unsigned*)(Hw + lane * KSTR);
        *(uint4*)(mrow)      = make_uint4(w0, w1, w2, w3);
        *(uint4*)(mrow + 4)  = make_uint4(w4, w5, 0u, 0u);
        *(uint4*)(mrow + 8)  = make_uint4(0u, 0u, 0u, 0u);
        *(uint4*)(mrow + 12) = make_uint4(0u, 0u, 0u, 0u);
    }
    // same-wave ds_write -> ds_read: ordered by lgkmcnt, no barrier needed

    // ---- layer 1 via MFMA: H[48x64] = msg[48x32] . W1[32x64] ----
    bf16x8 Am[3];
#pragma unroll
    for (int mt = 0; mt < 3; ++mt)
        Am[mt] = *(const bf16x8*)&Hw[(mt * 16 + col) * KSTR + quad * 8];

    const bf16x8* W1f = (const bf16x8*)w1f;
    float hreg[12][4];
#pragma unroll
    for (int nt = 0; nt < 4; ++nt) {
        bf16x8 Bn = W1f[nt * 64 + lane];
        const float bias = b1[nt * 16 + col];
        f32x4 d0 = {bias, bias, bias, bias};
        f32x4 d1 = d0, d2 = d0;
        d0 = __builtin_amdgcn_mfma_f32_16x16x32_bf16(Am[0], Bn, d0, 0, 0, 0);
        d1 = __builtin_amdgcn_mfma_f32_16x16x32_bf16(Am[1], Bn, d1, 0, 0, 0);
        d2 = __builtin_amdgcn_mfma_f32_16x16x32_bf16(Am[2], Bn, d2, 0, 0, 0);
#pragma unroll
        for (int r = 0; r < 4; ++r) {
            hreg[nt * 3 + 0][r] = fmaxf(d0[r], 0.0f);
            hreg[nt * 3 + 1][r] = fmaxf(d1[r], 0.0f);
            hreg[nt * 3 + 2][r] = fmaxf(d2[r], 0.0f);
        }
    }

    // msg fully consumed -> overwrite region as Hh[row][hidden].
    // 2 cvt_pk per (nt,mt); >>16 write folds to ds_write_b16_d16_hi.
#pragma unroll
    for (int nt = 0; nt < 4; ++nt)
#pragma unroll
        for (int mt = 0; mt < 3; ++mt) {
            const unsigned p01 = cvt_pk_bf16(hreg[nt * 3 + mt][0], hreg[nt * 3 + mt][1]);
            const unsigned p23 = cvt_pk_bf16(hreg[nt * 3 + mt][2], hreg[nt * 3 + mt][3]);
            unsigned short* hb = &Hw[(mt * 16 + quad * 4) * HSTR + nt * 16 + col];
            hb[0 * HSTR] = (unsigned short)p01;
            hb[1 * HSTR] = (unsigned short)(p01 >> 16);
            hb[2 * HSTR] = (unsigned short)p23;
            hb[3 * HSTR] = (unsigned short)(p23 >> 16);
        }

    // ---- layer 2 via MFMA ----
    bf16x8 Af[3][2];
#pragma unroll
    for (int mt = 0; mt < 3; ++mt)
#pragma unroll
        for (int kt = 0; kt < 2; ++kt)
            Af[mt][kt] = *(const bf16x8*)&Hw[(mt * 16 + col) * HSTR + kt * 32 + quad * 8];

    const bf16x8* Bws = (const bf16x8*)w2f;
    float vmv[8];
#pragma unroll
    for (int nt = 0; nt < 8; ++nt) {
        bf16x8 B0 = Bws[nt * 128 + lane];
        bf16x8 B1 = Bws[nt * 128 + 64 + lane];

        f32x4 c0 = {0.f, 0.f, 0.f, 0.f};
        f32x4 c1 = {0.f, 0.f, 0.f, 0.f};
        f32x4 c2 = {0.f, 0.f, 0.f, 0.f};
        c0 = __builtin_amdgcn_mfma_f32_16x16x32_bf16(Af[0][0], B0, c0, 0, 0, 0);
        c1 = __builtin_amdgcn_mfma_f32_16x16x32_bf16(Af[1][0], B0, c1, 0, 0, 0);
        c2 = __builtin_amdgcn_mfma_f32_16x16x32_bf16(Af[2][0], B0, c2, 0, 0, 0);
        c0 = __builtin_amdgcn_mfma_f32_16x16x32_bf16(Af[0][1], B1, c0, 0, 0, 0);
        c1 = __builtin_amdgcn_mfma_f32_16x16x32_bf16(Af[1][1], B1, c1, 0, 0, 0);
        c2 = __builtin_amdgcn_mfma_f32_16x16x32_bf16(Af[2][1], B1, c2, 0, 0, 0);

        // balanced reduce (v_max3_f32-shaped: fmax(fmax(a,b),c) fuses)
        const float m0 = fmaxf(fmaxf(c0[0], c0[1]), c0[2]);
        const float m1 = fmaxf(fmaxf(c0[3], c1[0]), c1[1]);
        const float m2 = fmaxf(fmaxf(c1[2], c1[3]), c2[0]);
        const float m3 = fmaxf(fmaxf(c2[1], c2[2]), c2[3]);
        float vm = fmaxf(fmaxf(fmaxf(m0, m1), m2), m3);
        vm = fmaxf(vm, __shfl_xor(vm, 16));
        vm = fmaxf(vm, __shfl_xor(vm, 32));
        vmv[nt] = vm;          // nt compile-time (unrolled) -> stays in regs
    }

    // ---- epilogue: 2 coalesced wave-wide stores; b2 via 2 coalesced loads.
    {
        const float b2a = b2[lane];
        const float b2b = b2[64 + lane];
        const float sA1 = (lane & 16) ? vmv[1] : vmv[0];
        const float sA2 = (lane & 16) ? vmv[3] : vmv[2];
        const float vA  = ((lane & 32) ? sA2 : sA1) + b2a;
        const float sB1 = (lane & 16) ? vmv[5] : vmv[4];
        const float sB2 = (lane & 16) ? vmv[7] : vmv[6];
        const float vB  = ((lane & 32) ? sB2 : sB1) + b2b;
        out[(size_t)gi * O_DIM + lane]      = vA;
        out[(size_t)gi * O_DIM + 64 + lane] = vB;
    }
}

// ---------------------------------------------------------------------------
extern "C" void kernel_launch(void* const* d_in, const int* in_sizes, int n_in,
                              void* d_out, int out_size, void* d_ws, size_t ws_size,
                              hipStream_t stream) {
    const float* x   = (const float*)d_in[0];
    const float* pos = (const float*)d_in[1];
    const float* W1  = (const float*)d_in[2];
    const float* b1  = (const float*)d_in[3];
    const float* W2  = (const float*)d_in[4];
    const float* b2  = (const float*)d_in[5];
    float* out = (float*)d_out;
    unsigned short* ws = (unsigned short*)d_ws;

    const int pre = (ws_size >= (size_t)WS_NEED_B) ? 1 : 0;
    const int nblocks = KNN_BLOCKS + (pre ? 74 : 10);

    knn_prep_kernel<<<nblocks, 1024, 0, stream>>>(pos, W2, W1, x, ws, out);
    if (pre) {
        conv_kernel<1><<<(B_CLOUDS * N_NODES) / 4, 256, 0, stream>>>(
            x, pos, ws, ws + 8192, ws + WS_XBF_OFF, (const float*)(ws + WS_POS4_OFF),
            b1, b2, out);
    } else {
        conv_kernel<0><<<(B_CLOUDS * N_NODES) / 4, 256, 0, stream>>>(
            x, pos, ws, ws + 8192, ws + WS_XBF_OFF, (const float*)(ws + WS_POS4_OFF),
            b1, b2, out);
    }
}